// Round 1
// baseline (1040.842 us; speedup 1.0000x reference)
//
#include <hip/hip_runtime.h>
#include <math.h>

#define SEQLEN   4096
#define DIM_IN   1024
#define D_INNER  2048
#define N_HEADS  32
#define D_STATE  128
#define CONV_DIM 2304      // D_INNER + 2*D_STATE
#define D_IN_PROJ 4384     // 2*D_INNER + 2*D_STATE + N_HEADS
#define LN_EPS   1e-5f

// ---------------- zero init (for atomic KV accumulation) ----------------
__global__ __launch_bounds__(256) void zero_kernel(float* __restrict__ p, int n) {
    int i = blockIdx.x * 256 + threadIdx.x;
    int stride = gridDim.x * 256;
    for (; i < n; i += stride) p[i] = 0.0f;
}

// ---------------- generic NT GEMM: C[M,N] = A[M,K] * B[N,K]^T ----------------
// tile 128x128, BK=16, 256 threads, 8x8 per-thread microtile. fp32.
// M must be a multiple of 128 (true for all uses: M=4096); N guarded; K % 16 == 0.
__global__ __launch_bounds__(256)
void gemm_nt(const float* __restrict__ A, int lda,
             const float* __restrict__ B, int ldb,
             float* __restrict__ C, int ldc,
             int N, int K) {
    __shared__ float As[16][132];   // k-major, +4 pad
    __shared__ float Bs[16][132];
    const int m0 = blockIdx.y * 128;
    const int n0 = blockIdx.x * 128;
    const int tid = threadIdx.x;
    const int ty = tid >> 4;    // 0..15  (m direction, 8 rows each)
    const int tx = tid & 15;    // 0..15  (n direction, 8 cols each)

    float acc[8][8];
    #pragma unroll
    for (int i = 0; i < 8; ++i)
        #pragma unroll
        for (int j = 0; j < 8; ++j) acc[i][j] = 0.0f;

    for (int k0 = 0; k0 < K; k0 += 16) {
        // stage A,B tiles: 128 rows x 16 k each = 512 float4; 2 per thread per matrix
        #pragma unroll
        for (int it = 0; it < 2; ++it) {
            int q   = tid + it * 256;   // 0..511
            int row = q >> 2;           // 0..127
            int kk  = (q & 3) * 4;      // 0,4,8,12
            float4 va = *reinterpret_cast<const float4*>(
                &A[(size_t)(m0 + row) * lda + k0 + kk]);
            As[kk + 0][row] = va.x; As[kk + 1][row] = va.y;
            As[kk + 2][row] = va.z; As[kk + 3][row] = va.w;
            int col = n0 + row;
            float4 vb = make_float4(0.f, 0.f, 0.f, 0.f);
            if (col < N)
                vb = *reinterpret_cast<const float4*>(
                    &B[(size_t)col * ldb + k0 + kk]);
            Bs[kk + 0][row] = vb.x; Bs[kk + 1][row] = vb.y;
            Bs[kk + 2][row] = vb.z; Bs[kk + 3][row] = vb.w;
        }
        __syncthreads();
        #pragma unroll
        for (int k = 0; k < 16; ++k) {
            float a[8], b[8];
            *reinterpret_cast<float4*>(&a[0]) = *reinterpret_cast<const float4*>(&As[k][ty * 8]);
            *reinterpret_cast<float4*>(&a[4]) = *reinterpret_cast<const float4*>(&As[k][ty * 8 + 4]);
            *reinterpret_cast<float4*>(&b[0]) = *reinterpret_cast<const float4*>(&Bs[k][tx * 8]);
            *reinterpret_cast<float4*>(&b[4]) = *reinterpret_cast<const float4*>(&Bs[k][tx * 8 + 4]);
            #pragma unroll
            for (int i = 0; i < 8; ++i)
                #pragma unroll
                for (int j = 0; j < 8; ++j)
                    acc[i][j] = fmaf(a[i], b[j], acc[i][j]);
        }
        __syncthreads();
    }

    #pragma unroll
    for (int i = 0; i < 8; ++i) {
        int row = m0 + ty * 8 + i;
        #pragma unroll
        for (int j = 0; j < 8; j += 4) {
            int col = n0 + tx * 8 + j;
            if (col < N) {   // col%4==0 and N%32==0 => whole float4 in range
                float4 v = make_float4(acc[i][j], acc[i][j+1], acc[i][j+2], acc[i][j+3]);
                *reinterpret_cast<float4*>(&C[(size_t)row * ldc + col]) = v;
            }
        }
    }
}

// ---------------- conv(width4, SAME) + SiLU on xbc; softplus(dt)*A ----------------
// SAME pad for k=4,stride=1 => pad_lo=1, pad_hi=2: out[t] = sum_j w[j]*x[t-1+j]
__global__ __launch_bounds__(256)
void conv_silu_kernel(const float* __restrict__ zxbcdt,
                      const float* __restrict__ conv_w,
                      const float* __restrict__ conv_b,
                      const float* __restrict__ dt_bias,
                      const float* __restrict__ A_log,
                      float* __restrict__ xbcs,
                      float* __restrict__ dA) {
    const int l = blockIdx.x;
    const float* base = zxbcdt + (size_t)l * D_IN_PROJ + D_INNER;  // xbc row l
    for (int c = threadIdx.x; c < CONV_DIM; c += 256) {
        float w0 = conv_w[c * 4 + 0], w1 = conv_w[c * 4 + 1];
        float w2 = conv_w[c * 4 + 2], w3 = conv_w[c * 4 + 3];
        float acc = conv_b[c];
        if (l >= 1)          acc += w0 * base[c - D_IN_PROJ];
        acc += w1 * base[c];
        if (l + 1 < SEQLEN)  acc += w2 * base[c + D_IN_PROJ];
        if (l + 2 < SEQLEN)  acc += w3 * base[c + 2 * D_IN_PROJ];
        float s = acc / (1.0f + expf(-acc));     // silu
        xbcs[(size_t)l * CONV_DIM + c] = s;
    }
    if (threadIdx.x < N_HEADS) {
        int h = threadIdx.x;
        float v = zxbcdt[(size_t)l * D_IN_PROJ + (D_IN_PROJ - N_HEADS) + h] + dt_bias[h];
        float sp = (v > 20.0f) ? v : log1pf(expf(v));     // softplus
        dA[l * N_HEADS + h] = sp * (-expf(A_log[h]));     // dt * A
    }
}

// ---------------- KVT[hp, n] += sum_l Vs[l,hp] * B[l,n] ----------------
// grid: (16 hp-tiles, 16 l-chunks of 256). tile 128hp x 128n, slabs of 16 l.
__global__ __launch_bounds__(256)
void kv_kernel(const float* __restrict__ xbcs,
               const float* __restrict__ dA,
               float* __restrict__ KVT) {
    __shared__ float Vs[16][132];
    __shared__ float Bsm[16][132];
    const int hp0 = blockIdx.x * 128;
    const int lc0 = blockIdx.y * 256;
    const int tid = threadIdx.x;
    const int ty = tid >> 4, tx = tid & 15;
    float acc[8][8];
    #pragma unroll
    for (int i = 0; i < 8; ++i)
        #pragma unroll
        for (int j = 0; j < 8; ++j) acc[i][j] = 0.0f;

    for (int ls = 0; ls < 256; ls += 16) {
        #pragma unroll
        for (int it = 0; it < 2; ++it) {
            int q    = tid + it * 256;  // 0..511 float4 slots
            int lrow = q >> 5;          // 0..15
            int p4   = (q & 31) * 4;    // 0..124
            int l = lc0 + ls + lrow;
            float4 v = *reinterpret_cast<const float4*>(
                &xbcs[(size_t)l * CONV_DIM + hp0 + p4]);
            float a = dA[l * N_HEADS + ((hp0 + p4) >> 6)];  // same head for all 4
            float4 vs = make_float4(v.x * a, v.y * a, v.z * a, v.w * a);
            *reinterpret_cast<float4*>(&Vs[lrow][p4]) = vs;
            float4 b = *reinterpret_cast<const float4*>(
                &xbcs[(size_t)l * CONV_DIM + D_INNER + p4]);
            *reinterpret_cast<float4*>(&Bsm[lrow][p4]) = b;
        }
        __syncthreads();
        #pragma unroll
        for (int k = 0; k < 16; ++k) {
            float a[8], b[8];
            *reinterpret_cast<float4*>(&a[0]) = *reinterpret_cast<const float4*>(&Vs[k][ty * 8]);
            *reinterpret_cast<float4*>(&a[4]) = *reinterpret_cast<const float4*>(&Vs[k][ty * 8 + 4]);
            *reinterpret_cast<float4*>(&b[0]) = *reinterpret_cast<const float4*>(&Bsm[k][tx * 8]);
            *reinterpret_cast<float4*>(&b[4]) = *reinterpret_cast<const float4*>(&Bsm[k][tx * 8 + 4]);
            #pragma unroll
            for (int i = 0; i < 8; ++i)
                #pragma unroll
                for (int j = 0; j < 8; ++j)
                    acc[i][j] = fmaf(a[i], b[j], acc[i][j]);
        }
        __syncthreads();
    }
    #pragma unroll
    for (int i = 0; i < 8; ++i) {
        int hp = hp0 + ty * 8 + i;
        #pragma unroll
        for (int j = 0; j < 8; ++j) {
            int n = tx * 8 + j;
            atomicAdd(&KVT[(size_t)hp * D_STATE + n], acc[i][j]);
        }
    }
}

// ---------------- y = y1 + D*x_in ; LayerNorm ; * silu(z). In-place on y1. ----------------
__global__ __launch_bounds__(256)
void ln_gate_kernel(float* __restrict__ y1,
                    const float* __restrict__ xbcs,
                    const float* __restrict__ zxbcdt,
                    const float* __restrict__ Dp,
                    const float* __restrict__ ln_w,
                    const float* __restrict__ ln_b) {
    const int l = blockIdx.x;
    const int tid = threadIdx.x;
    float y[8], z[8];
    float sum = 0.f, sumsq = 0.f;
    #pragma unroll
    for (int it = 0; it < 2; ++it) {
        int c = tid * 4 + it * 1024;
        float4 v  = *reinterpret_cast<const float4*>(&y1[(size_t)l * D_INNER + c]);
        float4 xi = *reinterpret_cast<const float4*>(&xbcs[(size_t)l * CONV_DIM + c]);
        float4 zz = *reinterpret_cast<const float4*>(&zxbcdt[(size_t)l * D_IN_PROJ + c]);
        float d = Dp[c >> 6];
        float yv0 = v.x + xi.x * d, yv1 = v.y + xi.y * d;
        float yv2 = v.z + xi.z * d, yv3 = v.w + xi.w * d;
        y[it*4+0] = yv0; y[it*4+1] = yv1; y[it*4+2] = yv2; y[it*4+3] = yv3;
        z[it*4+0] = zz.x; z[it*4+1] = zz.y; z[it*4+2] = zz.z; z[it*4+3] = zz.w;
        sum   += yv0 + yv1 + yv2 + yv3;
        sumsq += yv0*yv0 + yv1*yv1 + yv2*yv2 + yv3*yv3;
    }
    // reduce over 4 waves
    #pragma unroll
    for (int off = 32; off > 0; off >>= 1) {
        sum   += __shfl_down(sum, off);
        sumsq += __shfl_down(sumsq, off);
    }
    __shared__ float red[8];
    int wid = tid >> 6;
    if ((tid & 63) == 0) { red[wid] = sum; red[4 + wid] = sumsq; }
    __syncthreads();
    sum   = red[0] + red[1] + red[2] + red[3];
    sumsq = red[4] + red[5] + red[6] + red[7];
    float mu  = sum * (1.0f / D_INNER);
    float var = sumsq * (1.0f / D_INNER) - mu * mu;
    float rs  = rsqrtf(var + LN_EPS);
    #pragma unroll
    for (int it = 0; it < 2; ++it) {
        int c = tid * 4 + it * 1024;
        float4 o;
        float* op = &o.x;
        #pragma unroll
        for (int j = 0; j < 4; ++j) {
            float yn = (y[it*4+j] - mu) * rs * ln_w[c + j] + ln_b[c + j];
            float zv = z[it*4+j];
            float g  = zv / (1.0f + expf(-zv));    // silu
            op[j] = yn * g;
        }
        *reinterpret_cast<float4*>(&y1[(size_t)l * D_INNER + c]) = o;
    }
}

extern "C" void kernel_launch(void* const* d_in, const int* in_sizes, int n_in,
                              void* d_out, int out_size, void* d_ws, size_t ws_size,
                              hipStream_t stream) {
    const float* x       = (const float*)d_in[0];   // (4096,1024)
    const float* W_in    = (const float*)d_in[1];   // (4384,1024)
    const float* conv_w  = (const float*)d_in[2];   // (2304,1,4)
    const float* conv_b  = (const float*)d_in[3];   // (2304,)
    const float* dt_bias = (const float*)d_in[4];   // (32,)
    const float* A_log   = (const float*)d_in[5];   // (32,)
    const float* Dp      = (const float*)d_in[6];   // (32,)
    const float* ln_w    = (const float*)d_in[7];   // (2048,)
    const float* ln_b    = (const float*)d_in[8];   // (2048,)
    const float* W_out   = (const float*)d_in[9];   // (1024,2048)
    float* out = (float*)d_out;                     // (4096,1024)

    float* ws = (float*)d_ws;
    float* zxbcdt = ws;                                   // 4096*4384
    float* xbcs   = zxbcdt + (size_t)SEQLEN * D_IN_PROJ;  // 4096*2304
    float* dA     = xbcs   + (size_t)SEQLEN * CONV_DIM;   // 4096*32
    float* KVT    = dA     + (size_t)SEQLEN * N_HEADS;    // 2048*128
    float* y1     = KVT    + (size_t)D_INNER * D_STATE;   // 4096*2048 (LN in-place)

    // 1) zxbcdt = x @ W_in^T        (M=4096, N=4384, K=1024)
    gemm_nt<<<dim3(35, 32), 256, 0, stream>>>(x, DIM_IN, W_in, DIM_IN,
                                              zxbcdt, D_IN_PROJ, D_IN_PROJ, DIM_IN);
    // 2) conv+silu -> xbcs ; softplus(dt)*A -> dA
    conv_silu_kernel<<<SEQLEN, 256, 0, stream>>>(zxbcdt, conv_w, conv_b,
                                                 dt_bias, A_log, xbcs, dA);
    // 3) KVT = 0 ; KVT[hp,n] = sum_l Vs[l,hp]*B[l,n]
    zero_kernel<<<256, 256, 0, stream>>>(KVT, D_INNER * D_STATE);
    kv_kernel<<<dim3(16, 16), 256, 0, stream>>>(xbcs, dA, KVT);
    // 4) y1 = C @ KVT^T             (M=4096, N=2048, K=128); A = C-part of xbcs
    gemm_nt<<<dim3(16, 32), 256, 0, stream>>>(xbcs + (D_INNER + D_STATE), CONV_DIM,
                                              KVT, D_STATE, y1, D_INNER,
                                              D_INNER, D_STATE);
    // 5) y = LN(y1 + D*x_in) * silu(z)   (in-place in y1)
    ln_gate_kernel<<<SEQLEN, 256, 0, stream>>>(y1, xbcs, zxbcdt, Dp, ln_w, ln_b);
    // 6) out = y1 @ W_out^T         (M=4096, N=1024, K=2048)
    gemm_nt<<<dim3(8, 32), 256, 0, stream>>>(y1, D_INNER, W_out, D_INNER,
                                             out, DIM_IN, DIM_IN, D_INNER);
}

// Round 2
// 377.834 us; speedup vs baseline: 2.7548x; 2.7548x over previous
//
#include <hip/hip_runtime.h>
#include <math.h>

#define SEQLEN    4096
#define DIM_IN    1024
#define D_INNER   2048
#define N_HEADS   32
#define D_STATE   128
#define CONV_DIM  2304      // D_INNER + 2*D_STATE
#define D_IN_PROJ 4384      // 2*D_INNER + 2*D_STATE + N_HEADS
#define PROJ_LD   4480      // padded to 35*128 so GEMM1 N-tiles need no guard
#define LN_EPS    1e-5f

typedef __attribute__((ext_vector_type(8))) short bf16x8;
typedef __attribute__((ext_vector_type(4))) float f32x4;
typedef __attribute__((ext_vector_type(8))) short short8;

__device__ __forceinline__ ushort f2bf(float f) {
    union { float f; unsigned u; } v; v.f = f;
    unsigned u = v.u + 0x7FFFu + ((v.u >> 16) & 1u);   // RNE
    return (ushort)(u >> 16);
}

__device__ __forceinline__ void gload16(const void* g, void* l) {
    __builtin_amdgcn_global_load_lds(
        (const __attribute__((address_space(1))) void*)g,
        (__attribute__((address_space(3))) void*)l, 16, 0, 0);
}

// ---------------- zero init ----------------
__global__ __launch_bounds__(256) void zero_kernel(float* __restrict__ p, int n) {
    int i = blockIdx.x * 256 + threadIdx.x;
    int stride = gridDim.x * 256;
    for (; i < n; i += stride) p[i] = 0.0f;
}

// ---------------- fp32 -> bf16 converts ----------------
__global__ __launch_bounds__(256)
void cvt_bf16(const float* __restrict__ in, ushort* __restrict__ out, int n8) {
    int i = blockIdx.x * 256 + threadIdx.x;
    if (i >= n8) return;
    float4 v0 = reinterpret_cast<const float4*>(in)[i * 2];
    float4 v1 = reinterpret_cast<const float4*>(in)[i * 2 + 1];
    short8 r;
    r[0] = f2bf(v0.x); r[1] = f2bf(v0.y); r[2] = f2bf(v0.z); r[3] = f2bf(v0.w);
    r[4] = f2bf(v1.x); r[5] = f2bf(v1.y); r[6] = f2bf(v1.z); r[7] = f2bf(v1.w);
    *reinterpret_cast<short8*>(&out[i * 8]) = r;
}

// W_in (4384x1024) -> bf16 (4480x1024), pad rows zero
__global__ __launch_bounds__(256)
void cvt_win(const float* __restrict__ in, ushort* __restrict__ out) {
    int i = blockIdx.x * 256 + threadIdx.x;          // group of 8
    const int n8 = PROJ_LD * DIM_IN / 8;
    if (i >= n8) return;
    int row = (i * 8) >> 10;                          // 1024 cols
    short8 r;
    if (row < D_IN_PROJ) {
        float4 v0 = reinterpret_cast<const float4*>(in)[i * 2];
        float4 v1 = reinterpret_cast<const float4*>(in)[i * 2 + 1];
        r[0] = f2bf(v0.x); r[1] = f2bf(v0.y); r[2] = f2bf(v0.z); r[3] = f2bf(v0.w);
        r[4] = f2bf(v1.x); r[5] = f2bf(v1.y); r[6] = f2bf(v1.z); r[7] = f2bf(v1.w);
    } else {
        r = (short8){0,0,0,0,0,0,0,0};
    }
    *reinterpret_cast<short8*>(&out[i * 8]) = r;
}

// ---------------- bf16 NT GEMM (m97 structure): C[M,N] = A[M,K] * B[N,K]^T ----------------
// 128x128 tile, BK=32, 256 thr (4 waves, 2x2), 4x4 16x16x32 frags/wave, global_load_lds w=16.
// All of M,N multiples of 128; K multiple of 32. fp32 out.
__global__ __launch_bounds__(256)
void gemm_bf16_nt(const ushort* __restrict__ A, int lda,
                  const ushort* __restrict__ B, int ldb,
                  float* __restrict__ C, int ldc, int K) {
    __shared__ ushort As[128 * 32];
    __shared__ ushort Bs[128 * 32];
    const int tid  = threadIdx.x;
    const int wave = tid >> 6;
    const int lane = tid & 63;
    const int m0 = blockIdx.y * 128;
    const int n0 = blockIdx.x * 128;
    const int wm = (wave & 1) * 64;
    const int wn = (wave >> 1) * 64;
    const int r16 = lane & 15;
    const int kg  = lane >> 4;

    f32x4 acc[4][4];
    #pragma unroll
    for (int i = 0; i < 4; ++i)
        #pragma unroll
        for (int j = 0; j < 4; ++j) acc[i][j] = (f32x4){0.f, 0.f, 0.f, 0.f};

    // staging: 8 chunks of 16 rows (1KB) per matrix; wave w stages chunks 2w, 2w+1
    const int c0 = wave * 2, c1 = c0 + 1;
    const int srow = lane >> 2;          // row within chunk
    const int scol = (lane & 3) * 8;     // bf16 elements (16B)
    const ushort* ga0 = &A[(size_t)(m0 + c0 * 16 + srow) * lda + scol];
    const ushort* ga1 = &A[(size_t)(m0 + c1 * 16 + srow) * lda + scol];
    const ushort* gb0 = &B[(size_t)(n0 + c0 * 16 + srow) * ldb + scol];
    const ushort* gb1 = &B[(size_t)(n0 + c1 * 16 + srow) * ldb + scol];
    ushort* la0 = &As[c0 * 512];
    ushort* la1 = &As[c1 * 512];
    ushort* lb0 = &Bs[c0 * 512];
    ushort* lb1 = &Bs[c1 * 512];

    for (int k0 = 0; k0 < K; k0 += 32) {
        gload16(ga0 + k0, la0);
        gload16(ga1 + k0, la1);
        gload16(gb0 + k0, lb0);
        gload16(gb1 + k0, lb1);
        __syncthreads();

        bf16x8 a[4], b[4];
        #pragma unroll
        for (int mi = 0; mi < 4; ++mi)
            a[mi] = *reinterpret_cast<const bf16x8*>(&As[(wm + mi * 16 + r16) * 32 + kg * 8]);
        #pragma unroll
        for (int ni = 0; ni < 4; ++ni)
            b[ni] = *reinterpret_cast<const bf16x8*>(&Bs[(wn + ni * 16 + r16) * 32 + kg * 8]);
        #pragma unroll
        for (int mi = 0; mi < 4; ++mi)
            #pragma unroll
            for (int ni = 0; ni < 4; ++ni)
                acc[mi][ni] = __builtin_amdgcn_mfma_f32_16x16x32_bf16(a[mi], b[ni], acc[mi][ni], 0, 0, 0);
        __syncthreads();
    }

    // C/D layout (m89-verified): col = lane&15, row = (lane>>4)*4 + reg
    #pragma unroll
    for (int mi = 0; mi < 4; ++mi) {
        #pragma unroll
        for (int ni = 0; ni < 4; ++ni) {
            #pragma unroll
            for (int r = 0; r < 4; ++r) {
                int row = m0 + wm + mi * 16 + kg * 4 + r;
                int col = n0 + wn + ni * 16 + r16;
                C[(size_t)row * ldc + col] = acc[mi][ni][r];
            }
        }
    }
}

// ---------------- conv(width4, SAME) + SiLU ; softplus(dt)*A ; bf16 C-part ----------------
__global__ __launch_bounds__(256)
void conv_silu_kernel(const float* __restrict__ zxbcdt,
                      const float* __restrict__ conv_w,
                      const float* __restrict__ conv_b,
                      const float* __restrict__ dt_bias,
                      const float* __restrict__ A_log,
                      float* __restrict__ xbcs,
                      ushort* __restrict__ Cb16,
                      float* __restrict__ dA) {
    const int l = blockIdx.x;
    const float* base = zxbcdt + (size_t)l * PROJ_LD + D_INNER;
    for (int c = threadIdx.x; c < CONV_DIM; c += 256) {
        float w0 = conv_w[c * 4 + 0], w1 = conv_w[c * 4 + 1];
        float w2 = conv_w[c * 4 + 2], w3 = conv_w[c * 4 + 3];
        float acc = conv_b[c];
        if (l >= 1)          acc += w0 * base[c - PROJ_LD];
        acc += w1 * base[c];
        if (l + 1 < SEQLEN)  acc += w2 * base[c + PROJ_LD];
        if (l + 2 < SEQLEN)  acc += w3 * base[c + 2 * PROJ_LD];
        float s = acc / (1.0f + expf(-acc));     // silu
        xbcs[(size_t)l * CONV_DIM + c] = s;
        if (c >= D_INNER + D_STATE)
            Cb16[(size_t)l * D_STATE + (c - (D_INNER + D_STATE))] = f2bf(s);
    }
    if (threadIdx.x < N_HEADS) {
        int h = threadIdx.x;
        float v = zxbcdt[(size_t)l * PROJ_LD + (D_IN_PROJ - N_HEADS) + h] + dt_bias[h];
        float sp = (v > 20.0f) ? v : log1pf(expf(v));
        dA[l * N_HEADS + h] = sp * (-expf(A_log[h]));
    }
}

// ---------------- KVT[hp,n] += sum_l Vs[l,hp]*B[l,n]  (fp32, split over L) ----------------
__global__ __launch_bounds__(256)
void kv_kernel(const float* __restrict__ xbcs,
               const float* __restrict__ dA,
               float* __restrict__ KVT) {
    __shared__ float Vs[16][132];
    __shared__ float Bsm[16][132];
    const int hp0 = blockIdx.x * 128;
    const int lc0 = blockIdx.y * 256;
    const int tid = threadIdx.x;
    const int ty = tid >> 4, tx = tid & 15;
    float acc[8][8];
    #pragma unroll
    for (int i = 0; i < 8; ++i)
        #pragma unroll
        for (int j = 0; j < 8; ++j) acc[i][j] = 0.0f;

    for (int ls = 0; ls < 256; ls += 16) {
        #pragma unroll
        for (int it = 0; it < 2; ++it) {
            int q    = tid + it * 256;
            int lrow = q >> 5;
            int p4   = (q & 31) * 4;
            int l = lc0 + ls + lrow;
            float4 v = *reinterpret_cast<const float4*>(
                &xbcs[(size_t)l * CONV_DIM + hp0 + p4]);
            float a = dA[l * N_HEADS + ((hp0 + p4) >> 6)];
            float4 vs = make_float4(v.x * a, v.y * a, v.z * a, v.w * a);
            *reinterpret_cast<float4*>(&Vs[lrow][p4]) = vs;
            float4 b = *reinterpret_cast<const float4*>(
                &xbcs[(size_t)l * CONV_DIM + D_INNER + p4]);
            *reinterpret_cast<float4*>(&Bsm[lrow][p4]) = b;
        }
        __syncthreads();
        #pragma unroll
        for (int k = 0; k < 16; ++k) {
            float a[8], b[8];
            *reinterpret_cast<float4*>(&a[0]) = *reinterpret_cast<const float4*>(&Vs[k][ty * 8]);
            *reinterpret_cast<float4*>(&a[4]) = *reinterpret_cast<const float4*>(&Vs[k][ty * 8 + 4]);
            *reinterpret_cast<float4*>(&b[0]) = *reinterpret_cast<const float4*>(&Bsm[k][tx * 8]);
            *reinterpret_cast<float4*>(&b[4]) = *reinterpret_cast<const float4*>(&Bsm[k][tx * 8 + 4]);
            #pragma unroll
            for (int i = 0; i < 8; ++i)
                #pragma unroll
                for (int j = 0; j < 8; ++j)
                    acc[i][j] = fmaf(a[i], b[j], acc[i][j]);
        }
        __syncthreads();
    }
    #pragma unroll
    for (int i = 0; i < 8; ++i) {
        int hp = hp0 + ty * 8 + i;
        #pragma unroll
        for (int j = 0; j < 8; ++j) {
            int n = tx * 8 + j;
            atomicAdd(&KVT[(size_t)hp * D_STATE + n], acc[i][j]);
        }
    }
}

// ---------------- y = LN(y1 + D*x_in) * silu(z) -> bf16 ----------------
__global__ __launch_bounds__(256)
void ln_gate_kernel(const float* __restrict__ y1,
                    const float* __restrict__ xbcs,
                    const float* __restrict__ zxbcdt,
                    const float* __restrict__ Dp,
                    const float* __restrict__ ln_w,
                    const float* __restrict__ ln_b,
                    ushort* __restrict__ yb) {
    const int l = blockIdx.x;
    const int tid = threadIdx.x;
    float y[8], z[8];
    float sum = 0.f, sumsq = 0.f;
    #pragma unroll
    for (int it = 0; it < 2; ++it) {
        int c = tid * 4 + it * 1024;
        float4 v  = *reinterpret_cast<const float4*>(&y1[(size_t)l * D_INNER + c]);
        float4 xi = *reinterpret_cast<const float4*>(&xbcs[(size_t)l * CONV_DIM + c]);
        float4 zz = *reinterpret_cast<const float4*>(&zxbcdt[(size_t)l * PROJ_LD + c]);
        float d = Dp[c >> 6];
        float yv0 = v.x + xi.x * d, yv1 = v.y + xi.y * d;
        float yv2 = v.z + xi.z * d, yv3 = v.w + xi.w * d;
        y[it*4+0] = yv0; y[it*4+1] = yv1; y[it*4+2] = yv2; y[it*4+3] = yv3;
        z[it*4+0] = zz.x; z[it*4+1] = zz.y; z[it*4+2] = zz.z; z[it*4+3] = zz.w;
        sum   += yv0 + yv1 + yv2 + yv3;
        sumsq += yv0*yv0 + yv1*yv1 + yv2*yv2 + yv3*yv3;
    }
    #pragma unroll
    for (int off = 32; off > 0; off >>= 1) {
        sum   += __shfl_down(sum, off);
        sumsq += __shfl_down(sumsq, off);
    }
    __shared__ float red[8];
    int wid = tid >> 6;
    if ((tid & 63) == 0) { red[wid] = sum; red[4 + wid] = sumsq; }
    __syncthreads();
    sum   = red[0] + red[1] + red[2] + red[3];
    sumsq = red[4] + red[5] + red[6] + red[7];
    float mu  = sum * (1.0f / D_INNER);
    float var = sumsq * (1.0f / D_INNER) - mu * mu;
    float rs  = rsqrtf(var + LN_EPS);
    #pragma unroll
    for (int it = 0; it < 2; ++it) {
        int c = tid * 4 + it * 1024;
        ushort4 o;
        #pragma unroll
        for (int j = 0; j < 4; ++j) {
            float yn = (y[it*4+j] - mu) * rs * ln_w[c + j] + ln_b[c + j];
            float zv = z[it*4+j];
            float g  = zv / (1.0f + expf(-zv));
            float r  = yn * g;
            ((ushort*)&o)[j] = f2bf(r);
        }
        *reinterpret_cast<ushort4*>(&yb[(size_t)l * D_INNER + c]) = o;
    }
}

extern "C" void kernel_launch(void* const* d_in, const int* in_sizes, int n_in,
                              void* d_out, int out_size, void* d_ws, size_t ws_size,
                              hipStream_t stream) {
    const float* x       = (const float*)d_in[0];
    const float* W_in    = (const float*)d_in[1];
    const float* conv_w  = (const float*)d_in[2];
    const float* conv_b  = (const float*)d_in[3];
    const float* dt_bias = (const float*)d_in[4];
    const float* A_log   = (const float*)d_in[5];
    const float* Dp      = (const float*)d_in[6];
    const float* ln_w    = (const float*)d_in[7];
    const float* ln_b    = (const float*)d_in[8];
    const float* W_out   = (const float*)d_in[9];
    float* out = (float*)d_out;

    // workspace layout (bytes)
    char* ws = (char*)d_ws;
    float*  zxbcdt = (float*)ws;                               // 4096*4480*4 = 73,400,320
    float*  xbcs   = (float*)(ws + 73400320);                  // 4096*2304*4 = 37,748,736
    float*  y1     = (float*)(ws + 73400320 + 37748736);       // 4096*2048*4 = 33,554,432
    float*  dA     = (float*)(ws + 144703488);                 // 4096*32*4   =    524,288
    float*  KVT    = (float*)(ws + 145227776);                 // 2048*128*4  =  1,048,576
    ushort* Woutb  = (ushort*)(ws + 146276352);                // 1024*2048*2 =  4,194,304
    ushort* KVTb   = (ushort*)(ws + 150470656);                // 2048*128*2  =    524,288
    ushort* Cb16   = (ushort*)(ws + 150994944);                // 4096*128*2  =  1,048,576
    char*   regX   = ws + 152043520;                           // overlay region
    ushort* xb     = (ushort*)regX;                            // 4096*1024*2 =  8,388,608
    ushort* Winb   = (ushort*)(regX + 8388608);                // 4480*1024*2 =  9,175,040
    ushort* yb     = (ushort*)regX;                            // 4096*2048*2 = 16,777,216 (after GEMM1)

    // converts for GEMM1 + GEMM3 weights
    cvt_bf16<<<(SEQLEN * DIM_IN / 8 + 255) / 256, 256, 0, stream>>>(x, xb, SEQLEN * DIM_IN / 8);
    cvt_win<<<(PROJ_LD * DIM_IN / 8 + 255) / 256, 256, 0, stream>>>(W_in, Winb);
    cvt_bf16<<<(DIM_IN * D_INNER / 8 + 255) / 256, 256, 0, stream>>>(W_out, Woutb, DIM_IN * D_INNER / 8);

    // 1) zxbcdt = x @ W_in^T   (M=4096, N=4480(pad), K=1024)
    gemm_bf16_nt<<<dim3(PROJ_LD / 128, SEQLEN / 128), 256, 0, stream>>>(
        xb, DIM_IN, Winb, DIM_IN, zxbcdt, PROJ_LD, DIM_IN);

    // 2) conv + silu -> xbcs (+bf16 C) ; softplus(dt)*A -> dA
    conv_silu_kernel<<<SEQLEN, 256, 0, stream>>>(zxbcdt, conv_w, conv_b, dt_bias, A_log,
                                                 xbcs, Cb16, dA);

    // 3) KVT = sum_l Vs B  (fp32 atomally over 16 L-chunks)
    zero_kernel<<<256, 256, 0, stream>>>(KVT, D_INNER * D_STATE);
    kv_kernel<<<dim3(16, 16), 256, 0, stream>>>(xbcs, dA, KVT);
    cvt_bf16<<<(D_INNER * D_STATE / 8 + 255) / 256, 256, 0, stream>>>(KVT, KVTb, D_INNER * D_STATE / 8);

    // 4) y1 = C @ KVT^T  (M=4096, N=2048, K=128)
    gemm_bf16_nt<<<dim3(D_INNER / 128, SEQLEN / 128), 256, 0, stream>>>(
        Cb16, D_STATE, KVTb, D_STATE, y1, D_INNER, D_STATE);

    // 5) y = LN(y1 + D*x_in) * silu(z) -> bf16
    ln_gate_kernel<<<SEQLEN, 256, 0, stream>>>(y1, xbcs, zxbcdt, Dp, ln_w, ln_b, yb);

    // 6) out = y @ W_out^T  (M=4096, N=1024, K=2048)
    gemm_bf16_nt<<<dim3(DIM_IN / 128, SEQLEN / 128), 256, 0, stream>>>(
        yb, D_INNER, Woutb, D_INNER, out, DIM_IN, D_INNER);
}

// Round 3
// 249.728 us; speedup vs baseline: 4.1679x; 1.5130x over previous
//
#include <hip/hip_runtime.h>
#include <math.h>

#define SEQLEN    4096
#define DIM_IN    1024
#define D_INNER   2048
#define N_HEADS   32
#define D_STATE   128
#define CONV_DIM  2304      // D_INNER + 2*D_STATE
#define D_IN_PROJ 4384      // 2*D_INNER + 2*D_STATE + N_HEADS
#define PROJ_LD   4480      // padded to 35*128 so GEMM1 N-tiles need no guard
#define LN_EPS    1e-5f
#define KV_SPLIT  32        // L-chunks for the KV partial reduction

typedef __attribute__((ext_vector_type(8))) short bf16x8;
typedef __attribute__((ext_vector_type(4))) float f32x4;
typedef __attribute__((ext_vector_type(8))) short short8;

__device__ __forceinline__ ushort f2bf(float f) {
    union { float f; unsigned u; } v; v.f = f;
    unsigned u = v.u + 0x7FFFu + ((v.u >> 16) & 1u);   // RNE
    return (ushort)(u >> 16);
}

__device__ __forceinline__ void gload16(const void* g, void* l) {
    __builtin_amdgcn_global_load_lds(
        (const __attribute__((address_space(1))) void*)g,
        (__attribute__((address_space(3))) void*)l, 16, 0, 0);
}

// ---------------- fp32 -> bf16 converts ----------------
__global__ __launch_bounds__(256)
void cvt_bf16(const float* __restrict__ in, ushort* __restrict__ out, int n8) {
    int i = blockIdx.x * 256 + threadIdx.x;
    if (i >= n8) return;
    float4 v0 = reinterpret_cast<const float4*>(in)[i * 2];
    float4 v1 = reinterpret_cast<const float4*>(in)[i * 2 + 1];
    short8 r;
    r[0] = f2bf(v0.x); r[1] = f2bf(v0.y); r[2] = f2bf(v0.z); r[3] = f2bf(v0.w);
    r[4] = f2bf(v1.x); r[5] = f2bf(v1.y); r[6] = f2bf(v1.z); r[7] = f2bf(v1.w);
    *reinterpret_cast<short8*>(&out[i * 8]) = r;
}

// W_in (4384x1024) -> bf16 (4480x1024), pad rows zero
__global__ __launch_bounds__(256)
void cvt_win(const float* __restrict__ in, ushort* __restrict__ out) {
    int i = blockIdx.x * 256 + threadIdx.x;          // group of 8
    const int n8 = PROJ_LD * DIM_IN / 8;
    if (i >= n8) return;
    int row = (i * 8) >> 10;                          // 1024 cols
    short8 r;
    if (row < D_IN_PROJ) {
        float4 v0 = reinterpret_cast<const float4*>(in)[i * 2];
        float4 v1 = reinterpret_cast<const float4*>(in)[i * 2 + 1];
        r[0] = f2bf(v0.x); r[1] = f2bf(v0.y); r[2] = f2bf(v0.z); r[3] = f2bf(v0.w);
        r[4] = f2bf(v1.x); r[5] = f2bf(v1.y); r[6] = f2bf(v1.z); r[7] = f2bf(v1.w);
    } else {
        r = (short8){0,0,0,0,0,0,0,0};
    }
    *reinterpret_cast<short8*>(&out[i * 8]) = r;
}

// ---------------- bf16 NT GEMM (m97 structure): C[M,N] = A[M,K] * B[N,K]^T ----------------
__global__ __launch_bounds__(256)
void gemm_bf16_nt(const ushort* __restrict__ A, int lda,
                  const ushort* __restrict__ B, int ldb,
                  float* __restrict__ C, int ldc, int K) {
    __shared__ ushort As[128 * 32];
    __shared__ ushort Bs[128 * 32];
    const int tid  = threadIdx.x;
    const int wave = tid >> 6;
    const int lane = tid & 63;
    const int m0 = blockIdx.y * 128;
    const int n0 = blockIdx.x * 128;
    const int wm = (wave & 1) * 64;
    const int wn = (wave >> 1) * 64;
    const int r16 = lane & 15;
    const int kg  = lane >> 4;

    f32x4 acc[4][4];
    #pragma unroll
    for (int i = 0; i < 4; ++i)
        #pragma unroll
        for (int j = 0; j < 4; ++j) acc[i][j] = (f32x4){0.f, 0.f, 0.f, 0.f};

    const int c0 = wave * 2, c1 = c0 + 1;
    const int srow = lane >> 2;
    const int scol = (lane & 3) * 8;
    const ushort* ga0 = &A[(size_t)(m0 + c0 * 16 + srow) * lda + scol];
    const ushort* ga1 = &A[(size_t)(m0 + c1 * 16 + srow) * lda + scol];
    const ushort* gb0 = &B[(size_t)(n0 + c0 * 16 + srow) * ldb + scol];
    const ushort* gb1 = &B[(size_t)(n0 + c1 * 16 + srow) * ldb + scol];
    ushort* la0 = &As[c0 * 512];
    ushort* la1 = &As[c1 * 512];
    ushort* lb0 = &Bs[c0 * 512];
    ushort* lb1 = &Bs[c1 * 512];

    for (int k0 = 0; k0 < K; k0 += 32) {
        gload16(ga0 + k0, la0);
        gload16(ga1 + k0, la1);
        gload16(gb0 + k0, lb0);
        gload16(gb1 + k0, lb1);
        __syncthreads();

        bf16x8 a[4], b[4];
        #pragma unroll
        for (int mi = 0; mi < 4; ++mi)
            a[mi] = *reinterpret_cast<const bf16x8*>(&As[(wm + mi * 16 + r16) * 32 + kg * 8]);
        #pragma unroll
        for (int ni = 0; ni < 4; ++ni)
            b[ni] = *reinterpret_cast<const bf16x8*>(&Bs[(wn + ni * 16 + r16) * 32 + kg * 8]);
        #pragma unroll
        for (int mi = 0; mi < 4; ++mi)
            #pragma unroll
            for (int ni = 0; ni < 4; ++ni)
                acc[mi][ni] = __builtin_amdgcn_mfma_f32_16x16x32_bf16(a[mi], b[ni], acc[mi][ni], 0, 0, 0);
        __syncthreads();
    }

    #pragma unroll
    for (int mi = 0; mi < 4; ++mi) {
        #pragma unroll
        for (int ni = 0; ni < 4; ++ni) {
            #pragma unroll
            for (int r = 0; r < 4; ++r) {
                int row = m0 + wm + mi * 16 + kg * 4 + r;
                int col = n0 + wn + ni * 16 + r16;
                C[(size_t)row * ldc + col] = acc[mi][ni][r];
            }
        }
    }
}

// ---------------- conv(width4, SAME) + SiLU ; softplus(dt)*A ; bf16 C-part ----------------
__global__ __launch_bounds__(256)
void conv_silu_kernel(const float* __restrict__ zxbcdt,
                      const float* __restrict__ conv_w,
                      const float* __restrict__ conv_b,
                      const float* __restrict__ dt_bias,
                      const float* __restrict__ A_log,
                      float* __restrict__ xbcs,
                      ushort* __restrict__ Cb16,
                      float* __restrict__ dA) {
    const int l = blockIdx.x;
    const float* base = zxbcdt + (size_t)l * PROJ_LD + D_INNER;
    for (int c = threadIdx.x; c < CONV_DIM; c += 256) {
        float w0 = conv_w[c * 4 + 0], w1 = conv_w[c * 4 + 1];
        float w2 = conv_w[c * 4 + 2], w3 = conv_w[c * 4 + 3];
        float acc = conv_b[c];
        if (l >= 1)          acc += w0 * base[c - PROJ_LD];
        acc += w1 * base[c];
        if (l + 1 < SEQLEN)  acc += w2 * base[c + PROJ_LD];
        if (l + 2 < SEQLEN)  acc += w3 * base[c + 2 * PROJ_LD];
        float s = acc / (1.0f + expf(-acc));     // silu
        xbcs[(size_t)l * CONV_DIM + c] = s;
        if (c >= D_INNER + D_STATE)
            Cb16[(size_t)l * D_STATE + (c - (D_INNER + D_STATE))] = f2bf(s);
    }
    if (threadIdx.x < N_HEADS) {
        int h = threadIdx.x;
        float v = zxbcdt[(size_t)l * PROJ_LD + (D_IN_PROJ - N_HEADS) + h] + dt_bias[h];
        float sp = (v > 20.0f) ? v : log1pf(expf(v));
        dA[l * N_HEADS + h] = sp * (-expf(A_log[h]));
    }
}

// ---------------- KV partials: KVp[chunk][hp][n] = sum_{l in chunk} Vs[l,hp]*B[l,n] ----------------
// grid (16 hp-tiles, KV_SPLIT l-chunks of 128). No atomics: plain coalesced stores.
__global__ __launch_bounds__(256)
void kv_kernel(const float* __restrict__ xbcs,
               const float* __restrict__ dA,
               float* __restrict__ KVp) {
    __shared__ float Vs[16][132];
    __shared__ float Bsm[16][132];
    const int hp0 = blockIdx.x * 128;
    const int lc0 = blockIdx.y * (SEQLEN / KV_SPLIT);
    const int tid = threadIdx.x;
    const int ty = tid >> 4, tx = tid & 15;
    float acc[8][8];
    #pragma unroll
    for (int i = 0; i < 8; ++i)
        #pragma unroll
        for (int j = 0; j < 8; ++j) acc[i][j] = 0.0f;

    for (int ls = 0; ls < SEQLEN / KV_SPLIT; ls += 16) {
        #pragma unroll
        for (int it = 0; it < 2; ++it) {
            int q    = tid + it * 256;
            int lrow = q >> 5;
            int p4   = (q & 31) * 4;
            int l = lc0 + ls + lrow;
            float4 v = *reinterpret_cast<const float4*>(
                &xbcs[(size_t)l * CONV_DIM + hp0 + p4]);
            float a = dA[l * N_HEADS + ((hp0 + p4) >> 6)];
            float4 vs = make_float4(v.x * a, v.y * a, v.z * a, v.w * a);
            *reinterpret_cast<float4*>(&Vs[lrow][p4]) = vs;
            float4 b = *reinterpret_cast<const float4*>(
                &xbcs[(size_t)l * CONV_DIM + D_INNER + p4]);
            *reinterpret_cast<float4*>(&Bsm[lrow][p4]) = b;
        }
        __syncthreads();
        #pragma unroll
        for (int k = 0; k < 16; ++k) {
            float a[8], b[8];
            *reinterpret_cast<float4*>(&a[0]) = *reinterpret_cast<const float4*>(&Vs[k][ty * 8]);
            *reinterpret_cast<float4*>(&a[4]) = *reinterpret_cast<const float4*>(&Vs[k][ty * 8 + 4]);
            *reinterpret_cast<float4*>(&b[0]) = *reinterpret_cast<const float4*>(&Bsm[k][tx * 8]);
            *reinterpret_cast<float4*>(&b[4]) = *reinterpret_cast<const float4*>(&Bsm[k][tx * 8 + 4]);
            #pragma unroll
            for (int i = 0; i < 8; ++i)
                #pragma unroll
                for (int j = 0; j < 8; ++j)
                    acc[i][j] = fmaf(a[i], b[j], acc[i][j]);
        }
        __syncthreads();
    }
    float* dst = KVp + (size_t)blockIdx.y * (D_INNER * D_STATE);
    #pragma unroll
    for (int i = 0; i < 8; ++i) {
        int hp = hp0 + ty * 8 + i;
        #pragma unroll
        for (int j = 0; j < 8; j += 4) {
            float4 v = make_float4(acc[i][j], acc[i][j+1], acc[i][j+2], acc[i][j+3]);
            *reinterpret_cast<float4*>(&dst[(size_t)hp * D_STATE + tx * 8 + j]) = v;
        }
    }
}

// ---------------- reduce KV_SPLIT partial slices -> bf16 KVT ----------------
__global__ __launch_bounds__(256)
void kv_reduce(const float* __restrict__ KVp, ushort* __restrict__ KVTb) {
    int i = blockIdx.x * 256 + threadIdx.x;   // float4 index over 2048*128/4
    float4 s = make_float4(0.f, 0.f, 0.f, 0.f);
    #pragma unroll
    for (int c = 0; c < KV_SPLIT; ++c) {
        float4 v = reinterpret_cast<const float4*>(KVp + (size_t)c * (D_INNER * D_STATE))[i];
        s.x += v.x; s.y += v.y; s.z += v.z; s.w += v.w;
    }
    ushort4 o;
    o.x = f2bf(s.x); o.y = f2bf(s.y); o.z = f2bf(s.z); o.w = f2bf(s.w);
    *reinterpret_cast<ushort4*>(&KVTb[i * 4]) = o;
}

// ---------------- y = LN(y1 + D*x_in) * silu(z) -> bf16 ----------------
__global__ __launch_bounds__(256)
void ln_gate_kernel(const float* __restrict__ y1,
                    const float* __restrict__ xbcs,
                    const float* __restrict__ zxbcdt,
                    const float* __restrict__ Dp,
                    const float* __restrict__ ln_w,
                    const float* __restrict__ ln_b,
                    ushort* __restrict__ yb) {
    const int l = blockIdx.x;
    const int tid = threadIdx.x;
    float y[8], z[8];
    float sum = 0.f, sumsq = 0.f;
    #pragma unroll
    for (int it = 0; it < 2; ++it) {
        int c = tid * 4 + it * 1024;
        float4 v  = *reinterpret_cast<const float4*>(&y1[(size_t)l * D_INNER + c]);
        float4 xi = *reinterpret_cast<const float4*>(&xbcs[(size_t)l * CONV_DIM + c]);
        float4 zz = *reinterpret_cast<const float4*>(&zxbcdt[(size_t)l * PROJ_LD + c]);
        float d = Dp[c >> 6];
        float yv0 = v.x + xi.x * d, yv1 = v.y + xi.y * d;
        float yv2 = v.z + xi.z * d, yv3 = v.w + xi.w * d;
        y[it*4+0] = yv0; y[it*4+1] = yv1; y[it*4+2] = yv2; y[it*4+3] = yv3;
        z[it*4+0] = zz.x; z[it*4+1] = zz.y; z[it*4+2] = zz.z; z[it*4+3] = zz.w;
        sum   += yv0 + yv1 + yv2 + yv3;
        sumsq += yv0*yv0 + yv1*yv1 + yv2*yv2 + yv3*yv3;
    }
    #pragma unroll
    for (int off = 32; off > 0; off >>= 1) {
        sum   += __shfl_down(sum, off);
        sumsq += __shfl_down(sumsq, off);
    }
    __shared__ float red[8];
    int wid = tid >> 6;
    if ((tid & 63) == 0) { red[wid] = sum; red[4 + wid] = sumsq; }
    __syncthreads();
    sum   = red[0] + red[1] + red[2] + red[3];
    sumsq = red[4] + red[5] + red[6] + red[7];
    float mu  = sum * (1.0f / D_INNER);
    float var = sumsq * (1.0f / D_INNER) - mu * mu;
    float rs  = rsqrtf(var + LN_EPS);
    #pragma unroll
    for (int it = 0; it < 2; ++it) {
        int c = tid * 4 + it * 1024;
        ushort4 o;
        #pragma unroll
        for (int j = 0; j < 4; ++j) {
            float yn = (y[it*4+j] - mu) * rs * ln_w[c + j] + ln_b[c + j];
            float zv = z[it*4+j];
            float g  = zv / (1.0f + expf(-zv));
            float r  = yn * g;
            ((ushort*)&o)[j] = f2bf(r);
        }
        *reinterpret_cast<ushort4*>(&yb[(size_t)l * D_INNER + c]) = o;
    }
}

extern "C" void kernel_launch(void* const* d_in, const int* in_sizes, int n_in,
                              void* d_out, int out_size, void* d_ws, size_t ws_size,
                              hipStream_t stream) {
    const float* x       = (const float*)d_in[0];
    const float* W_in    = (const float*)d_in[1];
    const float* conv_w  = (const float*)d_in[2];
    const float* conv_b  = (const float*)d_in[3];
    const float* dt_bias = (const float*)d_in[4];
    const float* A_log   = (const float*)d_in[5];
    const float* Dp      = (const float*)d_in[6];
    const float* ln_w    = (const float*)d_in[7];
    const float* ln_b    = (const float*)d_in[8];
    const float* W_out   = (const float*)d_in[9];
    float* out = (float*)d_out;

    // workspace layout (bytes)
    char* ws = (char*)d_ws;
    float*  zxbcdt = (float*)ws;                               // 4096*4480*4 = 73,400,320
    float*  xbcs   = (float*)(ws + 73400320);                  // 4096*2304*4 = 37,748,736
    float*  y1     = (float*)(ws + 73400320 + 37748736);       // 4096*2048*4 = 33,554,432
    float*  KVp    = y1;                                       // KV partials overlay y1 (32 x 1 MB);
                                                               // consumed by kv_reduce BEFORE GEMM2 writes y1
    float*  dA     = (float*)(ws + 144703488);                 // 4096*32*4   =    524,288
    ushort* Woutb  = (ushort*)(ws + 146276352);                // 1024*2048*2 =  4,194,304
    ushort* KVTb   = (ushort*)(ws + 150470656);                // 2048*128*2  =    524,288
    ushort* Cb16   = (ushort*)(ws + 150994944);                // 4096*128*2  =  1,048,576
    char*   regX   = ws + 152043520;                           // overlay region
    ushort* xb     = (ushort*)regX;                            // 4096*1024*2 =  8,388,608
    ushort* Winb   = (ushort*)(regX + 8388608);                // 4480*1024*2 =  9,175,040
    ushort* yb     = (ushort*)regX;                            // 4096*2048*2 (after GEMM1)

    // converts for GEMM1 + GEMM3 weights
    cvt_bf16<<<(SEQLEN * DIM_IN / 8 + 255) / 256, 256, 0, stream>>>(x, xb, SEQLEN * DIM_IN / 8);
    cvt_win<<<(PROJ_LD * DIM_IN / 8 + 255) / 256, 256, 0, stream>>>(W_in, Winb);
    cvt_bf16<<<(DIM_IN * D_INNER / 8 + 255) / 256, 256, 0, stream>>>(W_out, Woutb, DIM_IN * D_INNER / 8);

    // 1) zxbcdt = x @ W_in^T   (M=4096, N=4480(pad), K=1024)
    gemm_bf16_nt<<<dim3(PROJ_LD / 128, SEQLEN / 128), 256, 0, stream>>>(
        xb, DIM_IN, Winb, DIM_IN, zxbcdt, PROJ_LD, DIM_IN);

    // 2) conv + silu -> xbcs (+bf16 C) ; softplus(dt)*A -> dA
    conv_silu_kernel<<<SEQLEN, 256, 0, stream>>>(zxbcdt, conv_w, conv_b, dt_bias, A_log,
                                                 xbcs, Cb16, dA);

    // 3) KV partials (no atomics) then reduce -> bf16 KVT
    kv_kernel<<<dim3(16, KV_SPLIT), 256, 0, stream>>>(xbcs, dA, KVp);
    kv_reduce<<<(D_INNER * D_STATE / 4) / 256, 256, 0, stream>>>(KVp, KVTb);

    // 4) y1 = C @ KVT^T  (M=4096, N=2048, K=128)
    gemm_bf16_nt<<<dim3(D_INNER / 128, SEQLEN / 128), 256, 0, stream>>>(
        Cb16, D_STATE, KVTb, D_STATE, y1, D_INNER, D_STATE);

    // 5) y = LN(y1 + D*x_in) * silu(z) -> bf16
    ln_gate_kernel<<<SEQLEN, 256, 0, stream>>>(y1, xbcs, zxbcdt, Dp, ln_w, ln_b, yb);

    // 6) out = y @ W_out^T  (M=4096, N=1024, K=2048)
    gemm_bf16_nt<<<dim3(DIM_IN / 128, SEQLEN / 128), 256, 0, stream>>>(
        yb, D_INNER, Woutb, D_INNER, out, DIM_IN, D_INNER);
}

// Round 4
// 241.846 us; speedup vs baseline: 4.3037x; 1.0326x over previous
//
#include <hip/hip_runtime.h>
#include <math.h>

#define SEQLEN    4096
#define DIM_IN    1024
#define D_INNER   2048
#define N_HEADS   32
#define D_STATE   128
#define CONV_DIM  2304      // D_INNER + 2*D_STATE
#define D_IN_PROJ 4384      // 2*D_INNER + 2*D_STATE + N_HEADS
#define PROJ_LD   4480      // padded to 35*128 so GEMM1 N-tiles need no guard
#define LN_EPS    1e-5f
#define KV_SPLIT  32        // L-chunks for the KV partial reduction

typedef __attribute__((ext_vector_type(8))) short bf16x8;
typedef __attribute__((ext_vector_type(4))) float f32x4;
typedef __attribute__((ext_vector_type(8))) short short8;

__device__ __forceinline__ ushort f2bf(float f) {
    union { float f; unsigned u; } v; v.f = f;
    unsigned u = v.u + 0x7FFFu + ((v.u >> 16) & 1u);   // RNE
    return (ushort)(u >> 16);
}

__device__ __forceinline__ void gload16(const void* g, void* l) {
    __builtin_amdgcn_global_load_lds(
        (const __attribute__((address_space(1))) void*)g,
        (__attribute__((address_space(3))) void*)l, 16, 0, 0);
}

// ---------------- fp32 -> bf16 converts ----------------
__global__ __launch_bounds__(256)
void cvt_bf16(const float* __restrict__ in, ushort* __restrict__ out, int n8) {
    int i = blockIdx.x * 256 + threadIdx.x;
    if (i >= n8) return;
    float4 v0 = reinterpret_cast<const float4*>(in)[i * 2];
    float4 v1 = reinterpret_cast<const float4*>(in)[i * 2 + 1];
    short8 r;
    r[0] = f2bf(v0.x); r[1] = f2bf(v0.y); r[2] = f2bf(v0.z); r[3] = f2bf(v0.w);
    r[4] = f2bf(v1.x); r[5] = f2bf(v1.y); r[6] = f2bf(v1.z); r[7] = f2bf(v1.w);
    *reinterpret_cast<short8*>(&out[i * 8]) = r;
}

// W_in (4384x1024) -> bf16 (4480x1024), pad rows zero
__global__ __launch_bounds__(256)
void cvt_win(const float* __restrict__ in, ushort* __restrict__ out) {
    int i = blockIdx.x * 256 + threadIdx.x;          // group of 8
    const int n8 = PROJ_LD * DIM_IN / 8;
    if (i >= n8) return;
    int row = (i * 8) >> 10;                          // 1024 cols
    short8 r;
    if (row < D_IN_PROJ) {
        float4 v0 = reinterpret_cast<const float4*>(in)[i * 2];
        float4 v1 = reinterpret_cast<const float4*>(in)[i * 2 + 1];
        r[0] = f2bf(v0.x); r[1] = f2bf(v0.y); r[2] = f2bf(v0.z); r[3] = f2bf(v0.w);
        r[4] = f2bf(v1.x); r[5] = f2bf(v1.y); r[6] = f2bf(v1.z); r[7] = f2bf(v1.w);
    } else {
        r = (short8){0,0,0,0,0,0,0,0};
    }
    *reinterpret_cast<short8*>(&out[i * 8]) = r;
}

// ---------------- pipelined bf16 NT GEMM: C[M,N] = A[M,K] * B[N,K]^T ----------------
// BM=128 fixed, BN template (128 or 64). BK=32, 4-deep LDS ring, counted vmcnt,
// XOR bank swizzle, XCD-aware block swizzle, setprio around MFMA.
// Requires: M%128==0, N%BN==0, K==NT*32, grid = (N/BN)*(M/128), grid%8==0.
template<int BN, int NT>
__global__ __launch_bounds__(256)
void gemm_bf16_pipe(const ushort* __restrict__ A, int lda,
                    const ushort* __restrict__ B, int ldb,
                    float* __restrict__ C, int ldc) {
    constexpr int NI = BN / 32;              // B frags per wave (strip = BN/2)
    __shared__ ushort As[4][128 * 32];
    __shared__ ushort Bs[4][BN * 32];

    // T1: bijective XCD swizzle (nwg % 8 == 0), by(M)-fastest so B-panels stay per-XCD
    const int nwg = gridDim.x;
    const int wg  = blockIdx.x;
    const int swz = (wg & 7) * (nwg >> 3) + (wg >> 3);
    const int by  = swz & 31;                // M-tile (M=4096 always -> 32 tiles)
    const int bx  = swz >> 5;                // N-tile
    const int m0 = by * 128;
    const int n0 = bx * BN;

    const int tid  = threadIdx.x;
    const int wave = tid >> 6;
    const int lane = tid & 63;
    const int wm = (wave & 1) * 64;
    const int wn = (wave >> 1) * (BN / 2);
    const int r16 = lane & 15;
    const int kg  = lane >> 4;
    const int pkg = kg ^ ((r16 >> 1) & 3);   // T2: swizzled k-slot for ds_read

    f32x4 acc[4][NI];
    #pragma unroll
    for (int i = 0; i < 4; ++i)
        #pragma unroll
        for (int j = 0; j < NI; ++j) acc[i][j] = (f32x4){0.f, 0.f, 0.f, 0.f};

    // staging geometry: chunks of 16 rows x 32 k (1KB). A: 8 chunks, B: BN/16.
    // per-lane source with inverse swizzle on the k-slot
    const int srow = lane >> 2;                               // row within chunk
    const int scol = ((lane & 3) ^ ((lane >> 3) & 3)) * 8;    // swizzled 16B slot
    const int ca0 = wave * 2, ca1 = wave * 2 + 1;
    const ushort* gA0 = A + (size_t)(m0 + ca0 * 16 + srow) * lda + scol;
    const ushort* gA1 = A + (size_t)(m0 + ca1 * 16 + srow) * lda + scol;
    const ushort* gB0;
    const ushort* gB1 = nullptr;
    int cb0, cb1 = 0;
    if constexpr (BN == 128) {
        cb0 = wave * 2; cb1 = wave * 2 + 1;
        gB0 = B + (size_t)(n0 + cb0 * 16 + srow) * ldb + scol;
        gB1 = B + (size_t)(n0 + cb1 * 16 + srow) * ldb + scol;
    } else {
        cb0 = wave;
        gB0 = B + (size_t)(n0 + cb0 * 16 + srow) * ldb + scol;
    }

#define STAGE_STEP(T)                                              \
    {                                                              \
        const int _b = (T) & 3;                                    \
        const int _k = (T) * 32;                                   \
        gload16(gA0 + _k, &As[_b][ca0 * 512]);                     \
        gload16(gA1 + _k, &As[_b][ca1 * 512]);                     \
        gload16(gB0 + _k, &Bs[_b][cb0 * 512]);                     \
        if constexpr (BN == 128) gload16(gB1 + _k, &Bs[_b][cb1 * 512]); \
    }

    // prologue: stage steps 0,1,2 (NT >= 4 for all users)
    STAGE_STEP(0)
    STAGE_STEP(1)
    STAGE_STEP(2)

    for (int t = 0; t < NT; ++t) {
        __builtin_amdgcn_sched_barrier(0);
        // counted wait: step t's loads landed; up to 2 steps stay in flight (T4)
        if (NT - t >= 3) {
            if constexpr (BN == 128) asm volatile("s_waitcnt vmcnt(8)" ::: "memory");
            else                     asm volatile("s_waitcnt vmcnt(6)" ::: "memory");
        } else if (NT - t == 2) {
            if constexpr (BN == 128) asm volatile("s_waitcnt vmcnt(4)" ::: "memory");
            else                     asm volatile("s_waitcnt vmcnt(3)" ::: "memory");
        } else {
            asm volatile("s_waitcnt vmcnt(0)" ::: "memory");
        }
        __builtin_amdgcn_s_barrier();
        __builtin_amdgcn_sched_barrier(0);

        if (t + 3 < NT) STAGE_STEP(t + 3)

        const ushort* ab = &As[t & 3][0];
        const ushort* bb = &Bs[t & 3][0];
        bf16x8 a[4], b[NI];
        #pragma unroll
        for (int mi = 0; mi < 4; ++mi)
            a[mi] = *reinterpret_cast<const bf16x8*>(&ab[(wm + mi * 16 + r16) * 32 + pkg * 8]);
        #pragma unroll
        for (int ni = 0; ni < NI; ++ni)
            b[ni] = *reinterpret_cast<const bf16x8*>(&bb[(wn + ni * 16 + r16) * 32 + pkg * 8]);

        __builtin_amdgcn_s_setprio(1);
        #pragma unroll
        for (int mi = 0; mi < 4; ++mi)
            #pragma unroll
            for (int ni = 0; ni < NI; ++ni)
                acc[mi][ni] = __builtin_amdgcn_mfma_f32_16x16x32_bf16(a[mi], b[ni], acc[mi][ni], 0, 0, 0);
        __builtin_amdgcn_s_setprio(0);
    }
#undef STAGE_STEP

    // C/D layout: col = lane&15, row = (lane>>4)*4 + reg
    #pragma unroll
    for (int mi = 0; mi < 4; ++mi) {
        #pragma unroll
        for (int ni = 0; ni < NI; ++ni) {
            #pragma unroll
            for (int r = 0; r < 4; ++r) {
                int row = m0 + wm + mi * 16 + kg * 4 + r;
                int col = n0 + wn + ni * 16 + r16;
                C[(size_t)row * ldc + col] = acc[mi][ni][r];
            }
        }
    }
}

// ---------------- conv(width4, SAME) + SiLU ; softplus(dt)*A ; bf16 C-part ----------------
__global__ __launch_bounds__(256)
void conv_silu_kernel(const float* __restrict__ zxbcdt,
                      const float* __restrict__ conv_w,
                      const float* __restrict__ conv_b,
                      const float* __restrict__ dt_bias,
                      const float* __restrict__ A_log,
                      float* __restrict__ xbcs,
                      ushort* __restrict__ Cb16,
                      float* __restrict__ dA) {
    const int l = blockIdx.x;
    const float* base = zxbcdt + (size_t)l * PROJ_LD + D_INNER;
    for (int c = threadIdx.x; c < CONV_DIM; c += 256) {
        float w0 = conv_w[c * 4 + 0], w1 = conv_w[c * 4 + 1];
        float w2 = conv_w[c * 4 + 2], w3 = conv_w[c * 4 + 3];
        float acc = conv_b[c];
        if (l >= 1)          acc += w0 * base[c - PROJ_LD];
        acc += w1 * base[c];
        if (l + 1 < SEQLEN)  acc += w2 * base[c + PROJ_LD];
        if (l + 2 < SEQLEN)  acc += w3 * base[c + 2 * PROJ_LD];
        float s = acc / (1.0f + expf(-acc));     // silu
        xbcs[(size_t)l * CONV_DIM + c] = s;
        if (c >= D_INNER + D_STATE)
            Cb16[(size_t)l * D_STATE + (c - (D_INNER + D_STATE))] = f2bf(s);
    }
    if (threadIdx.x < N_HEADS) {
        int h = threadIdx.x;
        float v = zxbcdt[(size_t)l * PROJ_LD + (D_IN_PROJ - N_HEADS) + h] + dt_bias[h];
        float sp = (v > 20.0f) ? v : log1pf(expf(v));
        dA[l * N_HEADS + h] = sp * (-expf(A_log[h]));
    }
}

// ---------------- KV partials: KVp[chunk][hp][n] = sum_{l in chunk} Vs[l,hp]*B[l,n] ----------------
__global__ __launch_bounds__(256)
void kv_kernel(const float* __restrict__ xbcs,
               const float* __restrict__ dA,
               float* __restrict__ KVp) {
    __shared__ float Vs[16][132];
    __shared__ float Bsm[16][132];
    const int hp0 = blockIdx.x * 128;
    const int lc0 = blockIdx.y * (SEQLEN / KV_SPLIT);
    const int tid = threadIdx.x;
    const int ty = tid >> 4, tx = tid & 15;
    float acc[8][8];
    #pragma unroll
    for (int i = 0; i < 8; ++i)
        #pragma unroll
        for (int j = 0; j < 8; ++j) acc[i][j] = 0.0f;

    for (int ls = 0; ls < SEQLEN / KV_SPLIT; ls += 16) {
        #pragma unroll
        for (int it = 0; it < 2; ++it) {
            int q    = tid + it * 256;
            int lrow = q >> 5;
            int p4   = (q & 31) * 4;
            int l = lc0 + ls + lrow;
            float4 v = *reinterpret_cast<const float4*>(
                &xbcs[(size_t)l * CONV_DIM + hp0 + p4]);
            float a = dA[l * N_HEADS + ((hp0 + p4) >> 6)];
            float4 vs = make_float4(v.x * a, v.y * a, v.z * a, v.w * a);
            *reinterpret_cast<float4*>(&Vs[lrow][p4]) = vs;
            float4 b = *reinterpret_cast<const float4*>(
                &xbcs[(size_t)l * CONV_DIM + D_INNER + p4]);
            *reinterpret_cast<float4*>(&Bsm[lrow][p4]) = b;
        }
        __syncthreads();
        #pragma unroll
        for (int k = 0; k < 16; ++k) {
            float a[8], b[8];
            *reinterpret_cast<float4*>(&a[0]) = *reinterpret_cast<const float4*>(&Vs[k][ty * 8]);
            *reinterpret_cast<float4*>(&a[4]) = *reinterpret_cast<const float4*>(&Vs[k][ty * 8 + 4]);
            *reinterpret_cast<float4*>(&b[0]) = *reinterpret_cast<const float4*>(&Bsm[k][tx * 8]);
            *reinterpret_cast<float4*>(&b[4]) = *reinterpret_cast<const float4*>(&Bsm[k][tx * 8 + 4]);
            #pragma unroll
            for (int i = 0; i < 8; ++i)
                #pragma unroll
                for (int j = 0; j < 8; ++j)
                    acc[i][j] = fmaf(a[i], b[j], acc[i][j]);
        }
        __syncthreads();
    }
    float* dst = KVp + (size_t)blockIdx.y * (D_INNER * D_STATE);
    #pragma unroll
    for (int i = 0; i < 8; ++i) {
        int hp = hp0 + ty * 8 + i;
        #pragma unroll
        for (int j = 0; j < 8; j += 4) {
            float4 v = make_float4(acc[i][j], acc[i][j+1], acc[i][j+2], acc[i][j+3]);
            *reinterpret_cast<float4*>(&dst[(size_t)hp * D_STATE + tx * 8 + j]) = v;
        }
    }
}

// ---------------- reduce KV_SPLIT partial slices -> bf16 KVT ----------------
__global__ __launch_bounds__(256)
void kv_reduce(const float* __restrict__ KVp, ushort* __restrict__ KVTb) {
    int i = blockIdx.x * 256 + threadIdx.x;   // float4 index over 2048*128/4
    float4 s = make_float4(0.f, 0.f, 0.f, 0.f);
    #pragma unroll
    for (int c = 0; c < KV_SPLIT; ++c) {
        float4 v = reinterpret_cast<const float4*>(KVp + (size_t)c * (D_INNER * D_STATE))[i];
        s.x += v.x; s.y += v.y; s.z += v.z; s.w += v.w;
    }
    ushort4 o;
    o.x = f2bf(s.x); o.y = f2bf(s.y); o.z = f2bf(s.z); o.w = f2bf(s.w);
    *reinterpret_cast<ushort4*>(&KVTb[i * 4]) = o;
}

// ---------------- y = LN(y1 + D*x_in) * silu(z) -> bf16 ----------------
__global__ __launch_bounds__(256)
void ln_gate_kernel(const float* __restrict__ y1,
                    const float* __restrict__ xbcs,
                    const float* __restrict__ zxbcdt,
                    const float* __restrict__ Dp,
                    const float* __restrict__ ln_w,
                    const float* __restrict__ ln_b,
                    ushort* __restrict__ yb) {
    const int l = blockIdx.x;
    const int tid = threadIdx.x;
    float y[8], z[8];
    float sum = 0.f, sumsq = 0.f;
    #pragma unroll
    for (int it = 0; it < 2; ++it) {
        int c = tid * 4 + it * 1024;
        float4 v  = *reinterpret_cast<const float4*>(&y1[(size_t)l * D_INNER + c]);
        float4 xi = *reinterpret_cast<const float4*>(&xbcs[(size_t)l * CONV_DIM + c]);
        float4 zz = *reinterpret_cast<const float4*>(&zxbcdt[(size_t)l * PROJ_LD + c]);
        float d = Dp[c >> 6];
        float yv0 = v.x + xi.x * d, yv1 = v.y + xi.y * d;
        float yv2 = v.z + xi.z * d, yv3 = v.w + xi.w * d;
        y[it*4+0] = yv0; y[it*4+1] = yv1; y[it*4+2] = yv2; y[it*4+3] = yv3;
        z[it*4+0] = zz.x; z[it*4+1] = zz.y; z[it*4+2] = zz.z; z[it*4+3] = zz.w;
        sum   += yv0 + yv1 + yv2 + yv3;
        sumsq += yv0*yv0 + yv1*yv1 + yv2*yv2 + yv3*yv3;
    }
    #pragma unroll
    for (int off = 32; off > 0; off >>= 1) {
        sum   += __shfl_down(sum, off);
        sumsq += __shfl_down(sumsq, off);
    }
    __shared__ float red[8];
    int wid = tid >> 6;
    if ((tid & 63) == 0) { red[wid] = sum; red[4 + wid] = sumsq; }
    __syncthreads();
    sum   = red[0] + red[1] + red[2] + red[3];
    sumsq = red[4] + red[5] + red[6] + red[7];
    float mu  = sum * (1.0f / D_INNER);
    float var = sumsq * (1.0f / D_INNER) - mu * mu;
    float rs  = rsqrtf(var + LN_EPS);
    #pragma unroll
    for (int it = 0; it < 2; ++it) {
        int c = tid * 4 + it * 1024;
        ushort4 o;
        #pragma unroll
        for (int j = 0; j < 4; ++j) {
            float yn = (y[it*4+j] - mu) * rs * ln_w[c + j] + ln_b[c + j];
            float zv = z[it*4+j];
            float g  = zv / (1.0f + expf(-zv));
            float r  = yn * g;
            ((ushort*)&o)[j] = f2bf(r);
        }
        *reinterpret_cast<ushort4*>(&yb[(size_t)l * D_INNER + c]) = o;
    }
}

extern "C" void kernel_launch(void* const* d_in, const int* in_sizes, int n_in,
                              void* d_out, int out_size, void* d_ws, size_t ws_size,
                              hipStream_t stream) {
    const float* x       = (const float*)d_in[0];
    const float* W_in    = (const float*)d_in[1];
    const float* conv_w  = (const float*)d_in[2];
    const float* conv_b  = (const float*)d_in[3];
    const float* dt_bias = (const float*)d_in[4];
    const float* A_log   = (const float*)d_in[5];
    const float* Dp      = (const float*)d_in[6];
    const float* ln_w    = (const float*)d_in[7];
    const float* ln_b    = (const float*)d_in[8];
    const float* W_out   = (const float*)d_in[9];
    float* out = (float*)d_out;

    // workspace layout (bytes)
    char* ws = (char*)d_ws;
    float*  zxbcdt = (float*)ws;                               // 4096*4480*4 = 73,400,320
    float*  xbcs   = (float*)(ws + 73400320);                  // 4096*2304*4 = 37,748,736
    float*  y1     = (float*)(ws + 73400320 + 37748736);       // 4096*2048*4 = 33,554,432
    float*  KVp    = y1;                                       // KV partials overlay y1 (32 x 1 MB);
                                                               // consumed by kv_reduce BEFORE GEMM2 writes y1
    float*  dA     = (float*)(ws + 144703488);                 // 4096*32*4   =    524,288
    ushort* Woutb  = (ushort*)(ws + 146276352);                // 1024*2048*2 =  4,194,304
    ushort* KVTb   = (ushort*)(ws + 150470656);                // 2048*128*2  =    524,288
    ushort* Cb16   = (ushort*)(ws + 150994944);                // 4096*128*2  =  1,048,576
    char*   regX   = ws + 152043520;                           // overlay region
    ushort* xb     = (ushort*)regX;                            // 4096*1024*2 =  8,388,608
    ushort* Winb   = (ushort*)(regX + 8388608);                // 4480*1024*2 =  9,175,040
    ushort* yb     = (ushort*)regX;                            // 4096*2048*2 (after GEMM1)

    // converts for GEMM1 + GEMM3 weights
    cvt_bf16<<<(SEQLEN * DIM_IN / 8 + 255) / 256, 256, 0, stream>>>(x, xb, SEQLEN * DIM_IN / 8);
    cvt_win<<<(PROJ_LD * DIM_IN / 8 + 255) / 256, 256, 0, stream>>>(W_in, Winb);
    cvt_bf16<<<(DIM_IN * D_INNER / 8 + 255) / 256, 256, 0, stream>>>(W_out, Woutb, DIM_IN * D_INNER / 8);

    // 1) zxbcdt = x @ W_in^T   (M=4096, N=4480(pad), K=1024) -> 1120 blocks
    gemm_bf16_pipe<128, 32><<<(PROJ_LD / 128) * 32, 256, 0, stream>>>(
        xb, DIM_IN, Winb, DIM_IN, zxbcdt, PROJ_LD);

    // 2) conv + silu -> xbcs (+bf16 C) ; softplus(dt)*A -> dA
    conv_silu_kernel<<<SEQLEN, 256, 0, stream>>>(zxbcdt, conv_w, conv_b, dt_bias, A_log,
                                                 xbcs, Cb16, dA);

    // 3) KV partials (no atomics) then reduce -> bf16 KVT
    kv_kernel<<<dim3(16, KV_SPLIT), 256, 0, stream>>>(xbcs, dA, KVp);
    kv_reduce<<<(D_INNER * D_STATE / 4) / 256, 256, 0, stream>>>(KVp, KVTb);

    // 4) y1 = C @ KVT^T  (M=4096, N=2048, K=128) -> 512 blocks
    gemm_bf16_pipe<128, 4><<<(D_INNER / 128) * 32, 256, 0, stream>>>(
        Cb16, D_STATE, KVTb, D_STATE, y1, D_INNER);

    // 5) y = LN(y1 + D*x_in) * silu(z) -> bf16
    ln_gate_kernel<<<SEQLEN, 256, 0, stream>>>(y1, xbcs, zxbcdt, Dp, ln_w, ln_b, yb);

    // 6) out = y @ W_out^T  (M=4096, N=1024, K=2048) -> 512 blocks (BN=64)
    gemm_bf16_pipe<64, 64><<<(DIM_IN / 64) * 32, 256, 0, stream>>>(
        yb, D_INNER, Woutb, D_INNER, out, DIM_IN);
}

// Round 6
// 224.668 us; speedup vs baseline: 4.6328x; 1.0765x over previous
//
#include <hip/hip_runtime.h>
#include <math.h>

#define SEQLEN    4096
#define DIM_IN    1024
#define D_INNER   2048
#define N_HEADS   32
#define D_STATE   128
#define CONV_DIM  2304      // D_INNER + 2*D_STATE
#define D_IN_PROJ 4384      // 2*D_INNER + 2*D_STATE + N_HEADS
#define PROJ_LD   4480      // padded to 35*128 so GEMM1 N-tiles need no guard
#define LN_EPS    1e-5f
#define KV_SPLIT  16        // L-chunks (256 l each) for the KV partial reduction

typedef __attribute__((ext_vector_type(8))) short bf16x8;
typedef __attribute__((ext_vector_type(4))) float f32x4;
typedef __attribute__((ext_vector_type(8))) short short8;

__device__ __forceinline__ ushort f2bf(float f) {
    union { float f; unsigned u; } v; v.f = f;
    unsigned u = v.u + 0x7FFFu + ((v.u >> 16) & 1u);   // RNE
    return (ushort)(u >> 16);
}
__device__ __forceinline__ float bf2f(ushort h) {
    union { unsigned u; float f; } v; v.u = ((unsigned)h) << 16;
    return v.f;
}

__device__ __forceinline__ void gload16(const void* g, void* l) {
    __builtin_amdgcn_global_load_lds(
        (const __attribute__((address_space(1))) void*)g,
        (__attribute__((address_space(3))) void*)l, 16, 0, 0);
}

// ---------------- fp32 -> bf16 converts ----------------
__global__ __launch_bounds__(256)
void cvt_bf16(const float* __restrict__ in, ushort* __restrict__ out, int n8) {
    int i = blockIdx.x * 256 + threadIdx.x;
    if (i >= n8) return;
    float4 v0 = reinterpret_cast<const float4*>(in)[i * 2];
    float4 v1 = reinterpret_cast<const float4*>(in)[i * 2 + 1];
    short8 r;
    r[0] = f2bf(v0.x); r[1] = f2bf(v0.y); r[2] = f2bf(v0.z); r[3] = f2bf(v0.w);
    r[4] = f2bf(v1.x); r[5] = f2bf(v1.y); r[6] = f2bf(v1.z); r[7] = f2bf(v1.w);
    *reinterpret_cast<short8*>(&out[i * 8]) = r;
}

// W_in (4384x1024) -> bf16 (4480x1024), pad rows zero
__global__ __launch_bounds__(256)
void cvt_win(const float* __restrict__ in, ushort* __restrict__ out) {
    int i = blockIdx.x * 256 + threadIdx.x;          // group of 8
    const int n8 = PROJ_LD * DIM_IN / 8;
    if (i >= n8) return;
    int row = (i * 8) >> 10;                          // 1024 cols
    short8 r;
    if (row < D_IN_PROJ) {
        float4 v0 = reinterpret_cast<const float4*>(in)[i * 2];
        float4 v1 = reinterpret_cast<const float4*>(in)[i * 2 + 1];
        r[0] = f2bf(v0.x); r[1] = f2bf(v0.y); r[2] = f2bf(v0.z); r[3] = f2bf(v0.w);
        r[4] = f2bf(v1.x); r[5] = f2bf(v1.y); r[6] = f2bf(v1.z); r[7] = f2bf(v1.w);
    } else {
        r = (short8){0,0,0,0,0,0,0,0};
    }
    *reinterpret_cast<short8*>(&out[i * 8]) = r;
}

// ---------------- pipelined bf16 NT GEMM: C[M,N] = A[M,K] * B[N,K]^T ----------------
// BM=128, BN in {128,64}. BK=32, 3-deep LDS ring (distance-2 prefetch, counted vmcnt),
// XOR bank swizzle, XCD swizzle, setprio. OUTBF: 1 -> bf16 C via LDS-staged coalesced
// stores; 0 -> fp32 direct stores.
// Requires: M==4096, N%BN==0, K==NT*32 (NT>=2), grid=(N/BN)*32, grid%8==0.
template<int BN, int NT, int OUTBF>
__global__ __launch_bounds__(256)
void gemm_bf16_pipe(const ushort* __restrict__ A, int lda,
                    const ushort* __restrict__ B, int ldb,
                    void* __restrict__ Cout, int ldc) {
    constexpr int NI  = BN / 32;             // B frags per wave (strip = BN/2)
    __shared__ ushort As[3][128 * 32];
    __shared__ ushort Bs[3][BN * 32];

    // T1: bijective XCD swizzle (nwg % 8 == 0), M-fastest
    const int nwg = gridDim.x;
    const int wg  = blockIdx.x;
    const int swz = (wg & 7) * (nwg >> 3) + (wg >> 3);
    const int m0 = (swz & 31) * 128;
    const int n0 = (swz >> 5) * BN;

    const int tid  = threadIdx.x;
    const int wave = tid >> 6;
    const int lane = tid & 63;
    const int wm = (wave & 1) * 64;
    const int wn = (wave >> 1) * (BN / 2);
    const int r16 = lane & 15;
    const int kg  = lane >> 4;
    const int pkg = kg ^ ((r16 >> 1) & 3);   // T2: swizzled k-slot for ds_read

    f32x4 acc[4][NI];
    #pragma unroll
    for (int i = 0; i < 4; ++i)
        #pragma unroll
        for (int j = 0; j < NI; ++j) acc[i][j] = (f32x4){0.f, 0.f, 0.f, 0.f};

    const int srow = lane >> 2;                               // row within 16-row chunk
    const int scol = ((lane & 3) ^ ((lane >> 3) & 3)) * 8;    // inverse-swizzled 16B slot
    const int ca0 = wave * 2, ca1 = wave * 2 + 1;
    const ushort* gA0 = A + (size_t)(m0 + ca0 * 16 + srow) * lda + scol;
    const ushort* gA1 = A + (size_t)(m0 + ca1 * 16 + srow) * lda + scol;
    const ushort* gB0;
    const ushort* gB1 = nullptr;
    int cb0, cb1 = 0;
    if constexpr (BN == 128) {
        cb0 = wave * 2; cb1 = wave * 2 + 1;
        gB0 = B + (size_t)(n0 + cb0 * 16 + srow) * ldb + scol;
        gB1 = B + (size_t)(n0 + cb1 * 16 + srow) * ldb + scol;
    } else {
        cb0 = wave;
        gB0 = B + (size_t)(n0 + cb0 * 16 + srow) * ldb + scol;
    }

#define STAGE_STEP(T, BUF)                                          \
    {                                                               \
        const int _k = (T) * 32;                                    \
        gload16(gA0 + _k, &As[BUF][ca0 * 512]);                     \
        gload16(gA1 + _k, &As[BUF][ca1 * 512]);                     \
        gload16(gB0 + _k, &Bs[BUF][cb0 * 512]);                     \
        if constexpr (BN == 128) gload16(gB1 + _k, &Bs[BUF][cb1 * 512]); \
    }

    STAGE_STEP(0, 0)
    STAGE_STEP(1, 1)

    int rb = 0;   // ring buffer holding step t
    for (int t = 0; t < NT; ++t) {
        __builtin_amdgcn_sched_barrier(0);
        if (t + 1 < NT) {   // steady: 2*LPS outstanding; drain step t's LPS
            if constexpr (BN == 128) asm volatile("s_waitcnt vmcnt(4)" ::: "memory");
            else                     asm volatile("s_waitcnt vmcnt(3)" ::: "memory");
        } else {
            asm volatile("s_waitcnt vmcnt(0)" ::: "memory");
        }
        __builtin_amdgcn_s_barrier();
        __builtin_amdgcn_sched_barrier(0);

        if (t + 2 < NT) {
            int sb = rb + 2; if (sb >= 3) sb -= 3;
            STAGE_STEP(t + 2, sb)
        }

        const ushort* ab = &As[rb][0];
        const ushort* bb = &Bs[rb][0];
        bf16x8 a[4], b[NI];
        #pragma unroll
        for (int mi = 0; mi < 4; ++mi)
            a[mi] = *reinterpret_cast<const bf16x8*>(&ab[(wm + mi * 16 + r16) * 32 + pkg * 8]);
        #pragma unroll
        for (int ni = 0; ni < NI; ++ni)
            b[ni] = *reinterpret_cast<const bf16x8*>(&bb[(wn + ni * 16 + r16) * 32 + pkg * 8]);

        __builtin_amdgcn_s_setprio(1);
        #pragma unroll
        for (int mi = 0; mi < 4; ++mi)
            #pragma unroll
            for (int ni = 0; ni < NI; ++ni)
                acc[mi][ni] = __builtin_amdgcn_mfma_f32_16x16x32_bf16(a[mi], b[ni], acc[mi][ni], 0, 0, 0);
        __builtin_amdgcn_s_setprio(0);

        rb = (rb == 2) ? 0 : rb + 1;
    }
#undef STAGE_STEP

    if constexpr (OUTBF) {
        // stage acc -> LDS (bf16) -> coalesced 16B global stores, 64 rows at a time
        ushort* EP = &As[0][0];             // 64*BN*2 bytes <= 24KB ring
        ushort* outp = (ushort*)Cout;
        __syncthreads();
        #pragma unroll
        for (int half = 0; half < 2; ++half) {
            if ((wave & 1) == half) {
                #pragma unroll
                for (int mi = 0; mi < 4; ++mi)
                    #pragma unroll
                    for (int ni = 0; ni < NI; ++ni)
                        #pragma unroll
                        for (int r = 0; r < 4; ++r)
                            EP[(mi * 16 + kg * 4 + r) * BN + wn + ni * 16 + r16] =
                                f2bf(acc[mi][ni][r]);
            }
            __syncthreads();
            #pragma unroll
            for (int i = 0; i < BN / 32; ++i) {
                int idx = tid + 256 * i;       // 16B chunks over 64 x BN bf16
                int row = idx / (BN / 8);
                int cb  = idx % (BN / 8);
                bf16x8 v = *reinterpret_cast<const bf16x8*>(&EP[row * BN + cb * 8]);
                *reinterpret_cast<bf16x8*>(
                    &outp[(size_t)(m0 + half * 64 + row) * ldc + n0 + cb * 8]) = v;
            }
            __syncthreads();
        }
    } else {
        float* outp = (float*)Cout;
        #pragma unroll
        for (int mi = 0; mi < 4; ++mi)
            #pragma unroll
            for (int ni = 0; ni < NI; ++ni)
                #pragma unroll
                for (int r = 0; r < 4; ++r) {
                    int row = m0 + wm + mi * 16 + kg * 4 + r;
                    int col = n0 + wn + ni * 16 + r16;
                    outp[(size_t)row * ldc + col] = acc[mi][ni][r];
                }
    }
}

// ---------------- conv(width4, SAME) + SiLU ; softplus(dt)*A ; all-bf16 ----------------
__global__ __launch_bounds__(256)
void conv_silu_kernel(const ushort* __restrict__ zxb,
                      const float* __restrict__ conv_w,
                      const float* __restrict__ conv_b,
                      const float* __restrict__ dt_bias,
                      const float* __restrict__ A_log,
                      ushort* __restrict__ xbcs,
                      float* __restrict__ dA) {
    const int l = blockIdx.x;
    const ushort* base = zxb + (size_t)l * PROJ_LD + D_INNER;
    for (int c = threadIdx.x; c < CONV_DIM; c += 256) {
        float w0 = conv_w[c * 4 + 0], w1 = conv_w[c * 4 + 1];
        float w2 = conv_w[c * 4 + 2], w3 = conv_w[c * 4 + 3];
        float acc = conv_b[c];
        if (l >= 1)          acc += w0 * bf2f(base[c - PROJ_LD]);
        acc += w1 * bf2f(base[c]);
        if (l + 1 < SEQLEN)  acc += w2 * bf2f(base[c + PROJ_LD]);
        if (l + 2 < SEQLEN)  acc += w3 * bf2f(base[c + 2 * PROJ_LD]);
        float s = acc / (1.0f + expf(-acc));     // silu
        xbcs[(size_t)l * CONV_DIM + c] = f2bf(s);
    }
    if (threadIdx.x < N_HEADS) {
        int h = threadIdx.x;
        float v = bf2f(zxb[(size_t)l * PROJ_LD + (D_IN_PROJ - N_HEADS) + h]) + dt_bias[h];
        float sp = (v > 20.0f) ? v : log1pf(expf(v));
        dA[l * N_HEADS + h] = sp * (-expf(A_log[h]));
    }
}

// ---------------- KV partials: KVp[chunk][hp][n] = sum_{l in chunk} Vs[l,hp]*B[l,n] ----------------
// bf16 inputs, fp32 accumulate, plain stores (no atomics). grid (16 hp-tiles, KV_SPLIT).
__global__ __launch_bounds__(256)
void kv_kernel(const ushort* __restrict__ xbcs,
               const float* __restrict__ dA,
               float* __restrict__ KVp) {
    __shared__ float Vs[16][132];
    __shared__ float Bsm[16][132];
    const int hp0 = blockIdx.x * 128;
    const int lc0 = blockIdx.y * (SEQLEN / KV_SPLIT);
    const int tid = threadIdx.x;
    const int ty = tid >> 4, tx = tid & 15;
    float acc[8][8];
    #pragma unroll
    for (int i = 0; i < 8; ++i)
        #pragma unroll
        for (int j = 0; j < 8; ++j) acc[i][j] = 0.0f;

    for (int ls = 0; ls < SEQLEN / KV_SPLIT; ls += 16) {
        {
            int lrow = tid >> 4;               // 0..15
            int p8   = (tid & 15) * 8;         // 0..120
            int l = lc0 + ls + lrow;
            short8 v = *reinterpret_cast<const short8*>(
                &xbcs[(size_t)l * CONV_DIM + hp0 + p8]);
            float a = dA[l * N_HEADS + ((hp0 + p8) >> 6)];
            #pragma unroll
            for (int j = 0; j < 8; ++j) Vs[lrow][p8 + j] = bf2f((ushort)v[j]) * a;
            short8 b = *reinterpret_cast<const short8*>(
                &xbcs[(size_t)l * CONV_DIM + D_INNER + p8]);
            #pragma unroll
            for (int j = 0; j < 8; ++j) Bsm[lrow][p8 + j] = bf2f((ushort)b[j]);
        }
        __syncthreads();
        #pragma unroll
        for (int k = 0; k < 16; ++k) {
            float a[8], b[8];
            *reinterpret_cast<float4*>(&a[0]) = *reinterpret_cast<const float4*>(&Vs[k][ty * 8]);
            *reinterpret_cast<float4*>(&a[4]) = *reinterpret_cast<const float4*>(&Vs[k][ty * 8 + 4]);
            *reinterpret_cast<float4*>(&b[0]) = *reinterpret_cast<const float4*>(&Bsm[k][tx * 8]);
            *reinterpret_cast<float4*>(&b[4]) = *reinterpret_cast<const float4*>(&Bsm[k][tx * 8 + 4]);
            #pragma unroll
            for (int i = 0; i < 8; ++i)
                #pragma unroll
                for (int j = 0; j < 8; ++j)
                    acc[i][j] = fmaf(a[i], b[j], acc[i][j]);
        }
        __syncthreads();
    }
    float* dst = KVp + (size_t)blockIdx.y * (D_INNER * D_STATE);
    #pragma unroll
    for (int i = 0; i < 8; ++i) {
        int hp = hp0 + ty * 8 + i;
        #pragma unroll
        for (int j = 0; j < 8; j += 4) {
            float4 v = make_float4(acc[i][j], acc[i][j+1], acc[i][j+2], acc[i][j+3]);
            *reinterpret_cast<float4*>(&dst[(size_t)hp * D_STATE + tx * 8 + j]) = v;
        }
    }
}

// ---------------- reduce KV_SPLIT partial slices -> bf16 KVT ----------------
__global__ __launch_bounds__(256)
void kv_reduce(const float* __restrict__ KVp, ushort* __restrict__ KVTb) {
    int i = blockIdx.x * 256 + threadIdx.x;   // float4 index over 2048*128/4
    float4 s = make_float4(0.f, 0.f, 0.f, 0.f);
    #pragma unroll
    for (int c = 0; c < KV_SPLIT; ++c) {
        float4 v = reinterpret_cast<const float4*>(KVp + (size_t)c * (D_INNER * D_STATE))[i];
        s.x += v.x; s.y += v.y; s.z += v.z; s.w += v.w;
    }
    ushort4 o;
    o.x = f2bf(s.x); o.y = f2bf(s.y); o.z = f2bf(s.z); o.w = f2bf(s.w);
    *reinterpret_cast<ushort4*>(&KVTb[i * 4]) = o;
}

// ---------------- y = LN(y1 + D*x_in) * silu(z) -> bf16 (all inputs bf16) ----------------
__global__ __launch_bounds__(256)
void ln_gate_kernel(const ushort* __restrict__ y1b,
                    const ushort* __restrict__ xbcs,
                    const ushort* __restrict__ zxb,
                    const float* __restrict__ Dp,
                    const float* __restrict__ ln_w,
                    const float* __restrict__ ln_b,
                    ushort* __restrict__ yb) {
    const int l = blockIdx.x;
    const int tid = threadIdx.x;
    const int c = tid * 8;
    float y[8], z[8];
    float sum = 0.f, sumsq = 0.f;
    {
        short8 v  = *reinterpret_cast<const short8*>(&y1b[(size_t)l * D_INNER + c]);
        short8 xi = *reinterpret_cast<const short8*>(&xbcs[(size_t)l * CONV_DIM + c]);
        short8 zz = *reinterpret_cast<const short8*>(&zxb[(size_t)l * PROJ_LD + c]);
        float d = Dp[c >> 6];
        #pragma unroll
        for (int j = 0; j < 8; ++j) {
            float yv = bf2f((ushort)v[j]) + bf2f((ushort)xi[j]) * d;
            y[j] = yv;
            z[j] = bf2f((ushort)zz[j]);
            sum += yv;
            sumsq += yv * yv;
        }
    }
    #pragma unroll
    for (int off = 32; off > 0; off >>= 1) {
        sum   += __shfl_down(sum, off);
        sumsq += __shfl_down(sumsq, off);
    }
    __shared__ float red[8];
    int wid = tid >> 6;
    if ((tid & 63) == 0) { red[wid] = sum; red[4 + wid] = sumsq; }
    __syncthreads();
    sum   = red[0] + red[1] + red[2] + red[3];
    sumsq = red[4] + red[5] + red[6] + red[7];
    float mu  = sum * (1.0f / D_INNER);
    float var = sumsq * (1.0f / D_INNER) - mu * mu;
    float rs  = rsqrtf(var + LN_EPS);
    short8 o;
    #pragma unroll
    for (int j = 0; j < 8; ++j) {
        float yn = (y[j] - mu) * rs * ln_w[c + j] + ln_b[c + j];
        float g  = z[j] / (1.0f + expf(-z[j]));
        o[j] = f2bf(yn * g);
    }
    *reinterpret_cast<short8*>(&yb[(size_t)l * D_INNER + c]) = o;
}

extern "C" void kernel_launch(void* const* d_in, const int* in_sizes, int n_in,
                              void* d_out, int out_size, void* d_ws, size_t ws_size,
                              hipStream_t stream) {
    const float* x       = (const float*)d_in[0];
    const float* W_in    = (const float*)d_in[1];
    const float* conv_w  = (const float*)d_in[2];
    const float* conv_b  = (const float*)d_in[3];
    const float* dt_bias = (const float*)d_in[4];
    const float* A_log   = (const float*)d_in[5];
    const float* Dp      = (const float*)d_in[6];
    const float* ln_w    = (const float*)d_in[7];
    const float* ln_b    = (const float*)d_in[8];
    const float* W_out   = (const float*)d_in[9];
    float* out = (float*)d_out;

    // workspace layout (bytes), all 256-aligned
    char* ws = (char*)d_ws;
    ushort* zxb   = (ushort*)ws;                       // 4096*4480*2 = 36,700,160
    ushort* xbcs  = (ushort*)(ws +  36700160);         // 4096*2304*2 = 18,874,368
    ushort* y1b   = (ushort*)(ws +  55574528);         // 4096*2048*2 = 16,777,216
    ushort* yb    = (ushort*)(ws +  72351744);         // 4096*2048*2 = 16,777,216
    float*  KVp   = (float*)(ws +  89128960);          // 16*2048*128*4 = 16,777,216
    float*  dA    = (float*)(ws + 105906176);          // 4096*32*4   =    524,288
    ushort* KVTb  = (ushort*)(ws + 106430464);         // 2048*128*2  =    524,288
    ushort* Woutb = (ushort*)(ws + 106954752);         // 1024*2048*2 =  4,194,304
    ushort* xb    = (ushort*)(ws + 111149056);         // 4096*1024*2 =  8,388,608
    ushort* Winb  = (ushort*)(ws + 119537664);         // 4480*1024*2 =  9,175,040

    // converts for GEMM1 + GEMM3 weights
    cvt_bf16<<<(SEQLEN * DIM_IN / 8 + 255) / 256, 256, 0, stream>>>(x, xb, SEQLEN * DIM_IN / 8);
    cvt_win<<<(PROJ_LD * DIM_IN / 8 + 255) / 256, 256, 0, stream>>>(W_in, Winb);
    cvt_bf16<<<(DIM_IN * D_INNER / 8 + 255) / 256, 256, 0, stream>>>(W_out, Woutb, DIM_IN * D_INNER / 8);

    // 1) zxb = bf16( x @ W_in^T )   (M=4096, N=4480(pad), K=1024) -> 1120 blocks
    gemm_bf16_pipe<128, 32, 1><<<(PROJ_LD / 128) * 32, 256, 0, stream>>>(
        xb, DIM_IN, Winb, DIM_IN, zxb, PROJ_LD);

    // 2) conv + silu -> bf16 xbcs ; softplus(dt)*A -> dA
    conv_silu_kernel<<<SEQLEN, 256, 0, stream>>>(zxb, conv_w, conv_b, dt_bias, A_log,
                                                 xbcs, dA);

    // 3) KV partials (no atomics) then reduce -> bf16 KVT
    kv_kernel<<<dim3(16, KV_SPLIT), 256, 0, stream>>>(xbcs, dA, KVp);
    kv_reduce<<<(D_INNER * D_STATE / 4) / 256, 256, 0, stream>>>(KVp, KVTb);

    // 4) y1b = bf16( Cmat @ KVT^T )  (M=4096, N=2048, K=128); A = C-slice of xbcs
    gemm_bf16_pipe<128, 4, 1><<<(D_INNER / 128) * 32, 256, 0, stream>>>(
        xbcs + (D_INNER + D_STATE), CONV_DIM, KVTb, D_STATE, y1b, D_INNER);

    // 5) y = LN(y1 + D*x_in) * silu(z) -> bf16 yb
    ln_gate_kernel<<<SEQLEN, 256, 0, stream>>>(y1b, xbcs, zxb, Dp, ln_w, ln_b, yb);

    // 6) out = y @ W_out^T  (M=4096, N=1024, K=2048) -> 512 blocks (BN=64), fp32 out
    gemm_bf16_pipe<64, 64, 0><<<(DIM_IN / 64) * 32, 256, 0, stream>>>(
        yb, D_INNER, Woutb, D_INNER, out, DIM_IN);
}

// Round 8
// 208.239 us; speedup vs baseline: 4.9983x; 1.0789x over previous
//
#include <hip/hip_runtime.h>
#include <math.h>

#define SEQLEN    4096
#define DIM_IN    1024
#define D_INNER   2048
#define N_HEADS   32
#define D_STATE   128
#define CONV_DIM  2304      // D_INNER + 2*D_STATE
#define D_IN_PROJ 4384      // 2*D_INNER + 2*D_STATE + N_HEADS
#define PROJ_LD   4480      // padded to 35*128 so GEMM1 N-tiles need no guard
#define LN_EPS    1e-5f
#define KV_SPLIT  16        // L-chunks (256 l each) for the KV partial reduction

typedef __attribute__((ext_vector_type(8))) short bf16x8;
typedef __attribute__((ext_vector_type(4))) float f32x4;
typedef __attribute__((ext_vector_type(8))) short short8;

__device__ __forceinline__ ushort f2bf(float f) {
    union { float f; unsigned u; } v; v.f = f;
    unsigned u = v.u + 0x7FFFu + ((v.u >> 16) & 1u);   // RNE
    return (ushort)(u >> 16);
}
__device__ __forceinline__ float bf2f(ushort h) {
    union { unsigned u; float f; } v; v.u = ((unsigned)h) << 16;
    return v.f;
}

__device__ __forceinline__ void gload16(const void* g, void* l) {
    __builtin_amdgcn_global_load_lds(
        (const __attribute__((address_space(1))) void*)g,
        (__attribute__((address_space(3))) void*)l, 16, 0, 0);
}

// ---------------- fp32 -> bf16 converts ----------------
__global__ __launch_bounds__(256)
void cvt_bf16(const float* __restrict__ in, ushort* __restrict__ out, int n8) {
    int i = blockIdx.x * 256 + threadIdx.x;
    if (i >= n8) return;
    float4 v0 = reinterpret_cast<const float4*>(in)[i * 2];
    float4 v1 = reinterpret_cast<const float4*>(in)[i * 2 + 1];
    short8 r;
    r[0] = f2bf(v0.x); r[1] = f2bf(v0.y); r[2] = f2bf(v0.z); r[3] = f2bf(v0.w);
    r[4] = f2bf(v1.x); r[5] = f2bf(v1.y); r[6] = f2bf(v1.z); r[7] = f2bf(v1.w);
    *reinterpret_cast<short8*>(&out[i * 8]) = r;
}

// W_in (4384x1024) -> bf16 (4480x1024), pad rows zero
__global__ __launch_bounds__(256)
void cvt_win(const float* __restrict__ in, ushort* __restrict__ out) {
    int i = blockIdx.x * 256 + threadIdx.x;          // group of 8
    const int n8 = PROJ_LD * DIM_IN / 8;
    if (i >= n8) return;
    int row = (i * 8) >> 10;                          // 1024 cols
    short8 r;
    if (row < D_IN_PROJ) {
        float4 v0 = reinterpret_cast<const float4*>(in)[i * 2];
        float4 v1 = reinterpret_cast<const float4*>(in)[i * 2 + 1];
        r[0] = f2bf(v0.x); r[1] = f2bf(v0.y); r[2] = f2bf(v0.z); r[3] = f2bf(v0.w);
        r[4] = f2bf(v1.x); r[5] = f2bf(v1.y); r[6] = f2bf(v1.z); r[7] = f2bf(v1.w);
    } else {
        r = (short8){0,0,0,0,0,0,0,0};
    }
    *reinterpret_cast<short8*>(&out[i * 8]) = r;
}

// ================= big-tile pipelined bf16 NT GEMM (GEMM1) =================
// C[M,N] = A[M,K] * B[N,K]^T, bf16 out. BM=256, BN=128, BK=32, 4 waves,
// per-wave 128x64 (12 ds_reads per 32 MFMA), ring-3 LDS, counted vmcnt(6),
// XOR bank swizzle, XCD swizzle, setprio. M==4096 (16 tiles), N%128==0.
template<int NT>
__global__ __launch_bounds__(256, 2)
void gemm_bf16_big(const ushort* __restrict__ A, int lda,
                   const ushort* __restrict__ B, int ldb,
                   ushort* __restrict__ Cout, int ldc) {
    // S[buf]: A-tile rows 0..255 at [0..8191], B-tile rows 0..127 at [8192..12287]
    __shared__ __align__(16) ushort S[3][12288];   // 72 KB

    const int nwg = gridDim.x;
    const int wg  = blockIdx.x;
    const int swz = (wg & 7) * (nwg >> 3) + (wg >> 3);   // bijective, nwg%8==0
    const int m0 = (swz & 15) * 256;                      // 16 M-tiles, M-fastest
    const int n0 = (swz >> 4) * 128;

    const int tid  = threadIdx.x;
    const int wave = tid >> 6;
    const int lane = tid & 63;
    const int wm = (wave >> 1) * 128;    // wave rows within tile
    const int wn = (wave & 1) * 64;      // wave cols
    const int r16 = lane & 15;
    const int kg  = lane >> 4;
    const int pkg = kg ^ ((r16 >> 1) & 3);   // T2 swizzled k-slot for ds_read

    f32x4 acc[8][4];
    #pragma unroll
    for (int i = 0; i < 8; ++i)
        #pragma unroll
        for (int j = 0; j < 4; ++j) acc[i][j] = (f32x4){0.f, 0.f, 0.f, 0.f};

    // staging: 24 chunks of 16 rows x 32 k (1 KB each); wave w stages chunks 6w..6w+5.
    // chunk c: c<16 -> A rows m0+16c.. ; else B rows n0+16(c-16).. ; LDS off = c*512.
    const int srow = lane >> 2;
    const int scol = ((lane & 3) ^ ((lane >> 3) & 3)) * 8;   // inverse-swizzled src slot
    const ushort* gsrc[6];
    #pragma unroll
    for (int i = 0; i < 6; ++i) {
        int c = wave * 6 + i;
        gsrc[i] = (c < 16)
            ? A + (size_t)(m0 + c * 16 + srow) * lda + scol
            : B + (size_t)(n0 + (c - 16) * 16 + srow) * ldb + scol;
    }

#define STAGE_BIG(T, BUF)                                            \
    {                                                                \
        const int _k = (T) * 32;                                     \
        _Pragma("unroll")                                            \
        for (int i = 0; i < 6; ++i)                                  \
            gload16(gsrc[i] + _k, &S[BUF][(wave * 6 + i) * 512]);    \
    }

    STAGE_BIG(0, 0)
    STAGE_BIG(1, 1)

    int rb = 0;
    for (int t = 0; t < NT; ++t) {
        __builtin_amdgcn_sched_barrier(0);
        if (t + 1 < NT) {   // steady: 12 outstanding; drain step t's 6
            asm volatile("s_waitcnt vmcnt(6)" ::: "memory");
        } else {
            asm volatile("s_waitcnt vmcnt(0)" ::: "memory");
        }
        __builtin_amdgcn_s_barrier();
        __builtin_amdgcn_sched_barrier(0);

        if (t + 2 < NT) {
            int sb = rb + 2; if (sb >= 3) sb -= 3;
            STAGE_BIG(t + 2, sb)
        }

        const ushort* sp = &S[rb][0];
        bf16x8 b4[4];
        #pragma unroll
        for (int ni = 0; ni < 4; ++ni)
            b4[ni] = *reinterpret_cast<const bf16x8*>(
                &sp[8192 + (wn + ni * 16 + r16) * 32 + pkg * 8]);
        #pragma unroll
        for (int mh = 0; mh < 2; ++mh) {
            bf16x8 a4[4];
            #pragma unroll
            for (int i = 0; i < 4; ++i)
                a4[i] = *reinterpret_cast<const bf16x8*>(
                    &sp[(wm + (mh * 4 + i) * 16 + r16) * 32 + pkg * 8]);
            __builtin_amdgcn_s_setprio(1);
            #pragma unroll
            for (int i = 0; i < 4; ++i)
                #pragma unroll
                for (int ni = 0; ni < 4; ++ni)
                    acc[mh * 4 + i][ni] = __builtin_amdgcn_mfma_f32_16x16x32_bf16(
                        a4[i], b4[ni], acc[mh * 4 + i][ni], 0, 0, 0);
            __builtin_amdgcn_s_setprio(0);
        }
        rb = (rb == 2) ? 0 : rb + 1;
    }
#undef STAGE_BIG

    // epilogue: acc -> LDS bf16 (padded stride 136 vs 128: kills 4-way ds_write
    // conflict, keeps 16B alignment) -> coalesced 16B stores, 128 rows/half
    ushort* EP = &S[0][0];                 // 128*136 = 17408 ushort <= 36864
    __syncthreads();
    #pragma unroll
    for (int half = 0; half < 2; ++half) {
        if ((wave >> 1) == half) {
            #pragma unroll
            for (int mi = 0; mi < 8; ++mi)
                #pragma unroll
                for (int ni = 0; ni < 4; ++ni)
                    #pragma unroll
                    for (int r = 0; r < 4; ++r)
                        EP[(mi * 16 + kg * 4 + r) * 136 + wn + ni * 16 + r16] =
                            f2bf(acc[mi][ni][r]);
        }
        __syncthreads();
        #pragma unroll
        for (int i = 0; i < 8; ++i) {
            int idx = tid + 256 * i;       // 2048 chunks of 16B over 128x128
            int row = idx >> 4;
            int cb  = idx & 15;
            bf16x8 v = *reinterpret_cast<const bf16x8*>(&EP[row * 136 + cb * 8]);
            *reinterpret_cast<bf16x8*>(
                &Cout[(size_t)(m0 + half * 128 + row) * ldc + n0 + cb * 8]) = v;
        }
        __syncthreads();
    }
}

// ---------------- pipelined bf16 NT GEMM (GEMM2/3): C[M,N] = A[M,K]*B[N,K]^T ----------------
// BM=128, BN in {128,64}. BK=32, 3-deep LDS ring, counted vmcnt, XOR swizzle,
// XCD swizzle, setprio. OUTBF: 1 -> bf16 out via padded-LDS staging; 0 -> fp32.
template<int BN, int NT, int OUTBF>
__global__ __launch_bounds__(256)
void gemm_bf16_pipe(const ushort* __restrict__ A, int lda,
                    const ushort* __restrict__ B, int ldb,
                    void* __restrict__ Cout, int ldc) {
    constexpr int NI  = BN / 32;             // B frags per wave (strip = BN/2)
    constexpr int BNP = BN + 8;              // padded epilogue stride (16B-aligned)
    __shared__ __align__(16) ushort As[3][128 * 32];
    __shared__ __align__(16) ushort Bs[3][BN * 32];

    const int nwg = gridDim.x;
    const int wg  = blockIdx.x;
    const int swz = (wg & 7) * (nwg >> 3) + (wg >> 3);
    const int m0 = (swz & 31) * 128;
    const int n0 = (swz >> 5) * BN;

    const int tid  = threadIdx.x;
    const int wave = tid >> 6;
    const int lane = tid & 63;
    const int wm = (wave & 1) * 64;
    const int wn = (wave >> 1) * (BN / 2);
    const int r16 = lane & 15;
    const int kg  = lane >> 4;
    const int pkg = kg ^ ((r16 >> 1) & 3);

    f32x4 acc[4][NI];
    #pragma unroll
    for (int i = 0; i < 4; ++i)
        #pragma unroll
        for (int j = 0; j < NI; ++j) acc[i][j] = (f32x4){0.f, 0.f, 0.f, 0.f};

    const int srow = lane >> 2;
    const int scol = ((lane & 3) ^ ((lane >> 3) & 3)) * 8;
    const int ca0 = wave * 2, ca1 = wave * 2 + 1;
    const ushort* gA0 = A + (size_t)(m0 + ca0 * 16 + srow) * lda + scol;
    const ushort* gA1 = A + (size_t)(m0 + ca1 * 16 + srow) * lda + scol;
    const ushort* gB0;
    const ushort* gB1 = nullptr;
    int cb0, cb1 = 0;
    if constexpr (BN == 128) {
        cb0 = wave * 2; cb1 = wave * 2 + 1;
        gB0 = B + (size_t)(n0 + cb0 * 16 + srow) * ldb + scol;
        gB1 = B + (size_t)(n0 + cb1 * 16 + srow) * ldb + scol;
    } else {
        cb0 = wave;
        gB0 = B + (size_t)(n0 + cb0 * 16 + srow) * ldb + scol;
    }

#define STAGE_STEP(T, BUF)                                          \
    {                                                               \
        const int _k = (T) * 32;                                    \
        gload16(gA0 + _k, &As[BUF][ca0 * 512]);                     \
        gload16(gA1 + _k, &As[BUF][ca1 * 512]);                     \
        gload16(gB0 + _k, &Bs[BUF][cb0 * 512]);                     \
        if constexpr (BN == 128) gload16(gB1 + _k, &Bs[BUF][cb1 * 512]); \
    }

    STAGE_STEP(0, 0)
    STAGE_STEP(1, 1)

    int rb = 0;
    for (int t = 0; t < NT; ++t) {
        __builtin_amdgcn_sched_barrier(0);
        if (t + 1 < NT) {
            if constexpr (BN == 128) asm volatile("s_waitcnt vmcnt(4)" ::: "memory");
            else                     asm volatile("s_waitcnt vmcnt(3)" ::: "memory");
        } else {
            asm volatile("s_waitcnt vmcnt(0)" ::: "memory");
        }
        __builtin_amdgcn_s_barrier();
        __builtin_amdgcn_sched_barrier(0);

        if (t + 2 < NT) {
            int sb = rb + 2; if (sb >= 3) sb -= 3;
            STAGE_STEP(t + 2, sb)
        }

        const ushort* ab = &As[rb][0];
        const ushort* bb = &Bs[rb][0];
        bf16x8 a[4], b[NI];
        #pragma unroll
        for (int mi = 0; mi < 4; ++mi)
            a[mi] = *reinterpret_cast<const bf16x8*>(&ab[(wm + mi * 16 + r16) * 32 + pkg * 8]);
        #pragma unroll
        for (int ni = 0; ni < NI; ++ni)
            b[ni] = *reinterpret_cast<const bf16x8*>(&bb[(wn + ni * 16 + r16) * 32 + pkg * 8]);

        __builtin_amdgcn_s_setprio(1);
        #pragma unroll
        for (int mi = 0; mi < 4; ++mi)
            #pragma unroll
            for (int ni = 0; ni < NI; ++ni)
                acc[mi][ni] = __builtin_amdgcn_mfma_f32_16x16x32_bf16(a[mi], b[ni], acc[mi][ni], 0, 0, 0);
        __builtin_amdgcn_s_setprio(0);

        rb = (rb == 2) ? 0 : rb + 1;
    }
#undef STAGE_STEP

    if constexpr (OUTBF) {
        ushort* EP = &As[0][0];             // 64*BNP*2 bytes fits the 24KB ring
        ushort* outp = (ushort*)Cout;
        __syncthreads();
        #pragma unroll
        for (int half = 0; half < 2; ++half) {
            if ((wave & 1) == half) {
                #pragma unroll
                for (int mi = 0; mi < 4; ++mi)
                    #pragma unroll
                    for (int ni = 0; ni < NI; ++ni)
                        #pragma unroll
                        for (int r = 0; r < 4; ++r)
                            EP[(mi * 16 + kg * 4 + r) * BNP + wn + ni * 16 + r16] =
                                f2bf(acc[mi][ni][r]);
            }
            __syncthreads();
            #pragma unroll
            for (int i = 0; i < BN / 32; ++i) {
                int idx = tid + 256 * i;       // 16B chunks over 64 x BN bf16
                int row = idx / (BN / 8);
                int cb  = idx % (BN / 8);
                bf16x8 v = *reinterpret_cast<const bf16x8*>(&EP[row * BNP + cb * 8]);
                *reinterpret_cast<bf16x8*>(
                    &outp[(size_t)(m0 + half * 64 + row) * ldc + n0 + cb * 8]) = v;
            }
            __syncthreads();
        }
    } else {
        float* outp = (float*)Cout;
        #pragma unroll
        for (int mi = 0; mi < 4; ++mi)
            #pragma unroll
            for (int ni = 0; ni < NI; ++ni)
                #pragma unroll
                for (int r = 0; r < 4; ++r) {
                    int row = m0 + wm + mi * 16 + kg * 4 + r;
                    int col = n0 + wn + ni * 16 + r16;
                    outp[(size_t)row * ldc + col] = acc[mi][ni][r];
                }
    }
}

// ---------------- conv(width4, SAME) + SiLU ; softplus(dt)*A ; all-bf16 ----------------
__global__ __launch_bounds__(256)
void conv_silu_kernel(const ushort* __restrict__ zxb,
                      const float* __restrict__ conv_w,
                      const float* __restrict__ conv_b,
                      const float* __restrict__ dt_bias,
                      const float* __restrict__ A_log,
                      ushort* __restrict__ xbcs,
                      float* __restrict__ dA) {
    const int l = blockIdx.x;
    const ushort* base = zxb + (size_t)l * PROJ_LD + D_INNER;
    for (int c = threadIdx.x; c < CONV_DIM; c += 256) {
        float w0 = conv_w[c * 4 + 0], w1 = conv_w[c * 4 + 1];
        float w2 = conv_w[c * 4 + 2], w3 = conv_w[c * 4 + 3];
        float acc = conv_b[c];
        if (l >= 1)          acc += w0 * bf2f(base[c - PROJ_LD]);
        acc += w1 * bf2f(base[c]);
        if (l + 1 < SEQLEN)  acc += w2 * bf2f(base[c + PROJ_LD]);
        if (l + 2 < SEQLEN)  acc += w3 * bf2f(base[c + 2 * PROJ_LD]);
        float s = acc / (1.0f + expf(-acc));     // silu
        xbcs[(size_t)l * CONV_DIM + c] = f2bf(s);
    }
    if (threadIdx.x < N_HEADS) {
        int h = threadIdx.x;
        float v = bf2f(zxb[(size_t)l * PROJ_LD + (D_IN_PROJ - N_HEADS) + h]) + dt_bias[h];
        float sp = (v > 20.0f) ? v : log1pf(expf(v));
        dA[l * N_HEADS + h] = sp * (-expf(A_log[h]));
    }
}

// ---------------- KV partials: KVp[chunk][hp][n] = sum_{l in chunk} Vs[l,hp]*B[l,n] ----------------
__global__ __launch_bounds__(256)
void kv_kernel(const ushort* __restrict__ xbcs,
               const float* __restrict__ dA,
               float* __restrict__ KVp) {
    __shared__ float Vs[16][132];
    __shared__ float Bsm[16][132];
    const int hp0 = blockIdx.x * 128;
    const int lc0 = blockIdx.y * (SEQLEN / KV_SPLIT);
    const int tid = threadIdx.x;
    const int ty = tid >> 4, tx = tid & 15;
    float acc[8][8];
    #pragma unroll
    for (int i = 0; i < 8; ++i)
        #pragma unroll
        for (int j = 0; j < 8; ++j) acc[i][j] = 0.0f;

    for (int ls = 0; ls < SEQLEN / KV_SPLIT; ls += 16) {
        {
            int lrow = tid >> 4;
            int p8   = (tid & 15) * 8;
            int l = lc0 + ls + lrow;
            short8 v = *reinterpret_cast<const short8*>(
                &xbcs[(size_t)l * CONV_DIM + hp0 + p8]);
            float a = dA[l * N_HEADS + ((hp0 + p8) >> 6)];
            #pragma unroll
            for (int j = 0; j < 8; ++j) Vs[lrow][p8 + j] = bf2f((ushort)v[j]) * a;
            short8 b = *reinterpret_cast<const short8*>(
                &xbcs[(size_t)l * CONV_DIM + D_INNER + p8]);
            #pragma unroll
            for (int j = 0; j < 8; ++j) Bsm[lrow][p8 + j] = bf2f((ushort)b[j]);
        }
        __syncthreads();
        #pragma unroll
        for (int k = 0; k < 16; ++k) {
            float a[8], b[8];
            *reinterpret_cast<float4*>(&a[0]) = *reinterpret_cast<const float4*>(&Vs[k][ty * 8]);
            *reinterpret_cast<float4*>(&a[4]) = *reinterpret_cast<const float4*>(&Vs[k][ty * 8 + 4]);
            *reinterpret_cast<float4*>(&b[0]) = *reinterpret_cast<const float4*>(&Bsm[k][tx * 8]);
            *reinterpret_cast<float4*>(&b[4]) = *reinterpret_cast<const float4*>(&Bsm[k][tx * 8 + 4]);
            #pragma unroll
            for (int i = 0; i < 8; ++i)
                #pragma unroll
                for (int j = 0; j < 8; ++j)
                    acc[i][j] = fmaf(a[i], b[j], acc[i][j]);
        }
        __syncthreads();
    }
    float* dst = KVp + (size_t)blockIdx.y * (D_INNER * D_STATE);
    #pragma unroll
    for (int i = 0; i < 8; ++i) {
        int hp = hp0 + ty * 8 + i;
        #pragma unroll
        for (int j = 0; j < 8; j += 4) {
            float4 v = make_float4(acc[i][j], acc[i][j+1], acc[i][j+2], acc[i][j+3]);
            *reinterpret_cast<float4*>(&dst[(size_t)hp * D_STATE + tx * 8 + j]) = v;
        }
    }
}

// ---------------- reduce KV_SPLIT partial slices -> bf16 KVT ----------------
__global__ __launch_bounds__(256)
void kv_reduce(const float* __restrict__ KVp, ushort* __restrict__ KVTb) {
    int i = blockIdx.x * 256 + threadIdx.x;
    float4 s = make_float4(0.f, 0.f, 0.f, 0.f);
    #pragma unroll
    for (int c = 0; c < KV_SPLIT; ++c) {
        float4 v = reinterpret_cast<const float4*>(KVp + (size_t)c * (D_INNER * D_STATE))[i];
        s.x += v.x; s.y += v.y; s.z += v.z; s.w += v.w;
    }
    ushort4 o;
    o.x = f2bf(s.x); o.y = f2bf(s.y); o.z = f2bf(s.z); o.w = f2bf(s.w);
    *reinterpret_cast<ushort4*>(&KVTb[i * 4]) = o;
}

// ---------------- y = LN(y1 + D*x_in) * silu(z) -> bf16 (all inputs bf16) ----------------
__global__ __launch_bounds__(256)
void ln_gate_kernel(const ushort* __restrict__ y1b,
                    const ushort* __restrict__ xbcs,
                    const ushort* __restrict__ zxb,
                    const float* __restrict__ Dp,
                    const float* __restrict__ ln_w,
                    const float* __restrict__ ln_b,
                    ushort* __restrict__ yb) {
    const int l = blockIdx.x;
    const int tid = threadIdx.x;
    const int c = tid * 8;
    float y[8], z[8];
    float sum = 0.f, sumsq = 0.f;
    {
        short8 v  = *reinterpret_cast<const short8*>(&y1b[(size_t)l * D_INNER + c]);
        short8 xi = *reinterpret_cast<const short8*>(&xbcs[(size_t)l * CONV_DIM + c]);
        short8 zz = *reinterpret_cast<const short8*>(&zxb[(size_t)l * PROJ_LD + c]);
        float d = Dp[c >> 6];
        #pragma unroll
        for (int j = 0; j < 8; ++j) {
            float yv = bf2f((ushort)v[j]) + bf2f((ushort)xi[j]) * d;
            y[j] = yv;
            z[j] = bf2f((ushort)zz[j]);
            sum += yv;
            sumsq += yv * yv;
        }
    }
    #pragma unroll
    for (int off = 32; off > 0; off >>= 1) {
        sum   += __shfl_down(sum, off);
        sumsq += __shfl_down(sumsq, off);
    }
    __shared__ float red[8];
    int wid = tid >> 6;
    if ((tid & 63) == 0) { red[wid] = sum; red[4 + wid] = sumsq; }
    __syncthreads();
    sum   = red[0] + red[1] + red[2] + red[3];
    sumsq = red[4] + red[5] + red[6] + red[7];
    float mu  = sum * (1.0f / D_INNER);
    float var = sumsq * (1.0f / D_INNER) - mu * mu;
    float rs  = rsqrtf(var + LN_EPS);
    short8 o;
    #pragma unroll
    for (int j = 0; j < 8; ++j) {
        float yn = (y[j] - mu) * rs * ln_w[c + j] + ln_b[c + j];
        float g  = z[j] / (1.0f + expf(-z[j]));
        o[j] = f2bf(yn * g);
    }
    *reinterpret_cast<short8*>(&yb[(size_t)l * D_INNER + c]) = o;
}

extern "C" void kernel_launch(void* const* d_in, const int* in_sizes, int n_in,
                              void* d_out, int out_size, void* d_ws, size_t ws_size,
                              hipStream_t stream) {
    const float* x       = (const float*)d_in[0];
    const float* W_in    = (const float*)d_in[1];
    const float* conv_w  = (const float*)d_in[2];
    const float* conv_b  = (const float*)d_in[3];
    const float* dt_bias = (const float*)d_in[4];
    const float* A_log   = (const float*)d_in[5];
    const float* Dp      = (const float*)d_in[6];
    const float* ln_w    = (const float*)d_in[7];
    const float* ln_b    = (const float*)d_in[8];
    const float* W_out   = (const float*)d_in[9];
    float* out = (float*)d_out;

    // workspace layout (bytes), all 256-aligned
    char* ws = (char*)d_ws;
    ushort* zxb   = (ushort*)ws;                       // 4096*4480*2 = 36,700,160
    ushort* xbcs  = (ushort*)(ws +  36700160);         // 4096*2304*2 = 18,874,368
    ushort* y1b   = (ushort*)(ws +  55574528);         // 4096*2048*2 = 16,777,216
    ushort* yb    = (ushort*)(ws +  72351744);         // 4096*2048*2 = 16,777,216
    float*  KVp   = (float*)(ws +  89128960);          // 16*2048*128*4 = 16,777,216
    float*  dA    = (float*)(ws + 105906176);          // 4096*32*4   =    524,288
    ushort* KVTb  = (ushort*)(ws + 106430464);         // 2048*128*2  =    524,288
    ushort* Woutb = (ushort*)(ws + 106954752);         // 1024*2048*2 =  4,194,304
    ushort* xb    = (ushort*)(ws + 111149056);         // 4096*1024*2 =  8,388,608
    ushort* Winb  = (ushort*)(ws + 119537664);         // 4480*1024*2 =  9,175,040

    // converts for GEMM1 + GEMM3 weights
    cvt_bf16<<<(SEQLEN * DIM_IN / 8 + 255) / 256, 256, 0, stream>>>(x, xb, SEQLEN * DIM_IN / 8);
    cvt_win<<<(PROJ_LD * DIM_IN / 8 + 255) / 256, 256, 0, stream>>>(W_in, Winb);
    cvt_bf16<<<(DIM_IN * D_INNER / 8 + 255) / 256, 256, 0, stream>>>(W_out, Woutb, DIM_IN * D_INNER / 8);

    // 1) zxb = bf16( x @ W_in^T )   (M=4096, N=4480(pad), K=1024) -> 560 big blocks
    gemm_bf16_big<32><<<16 * (PROJ_LD / 128), 256, 0, stream>>>(
        xb, DIM_IN, Winb, DIM_IN, zxb, PROJ_LD);

    // 2) conv + silu -> bf16 xbcs ; softplus(dt)*A -> dA
    conv_silu_kernel<<<SEQLEN, 256, 0, stream>>>(zxb, conv_w, conv_b, dt_bias, A_log,
                                                 xbcs, dA);

    // 3) KV partials (no atomics) then reduce -> bf16 KVT
    kv_kernel<<<dim3(16, KV_SPLIT), 256, 0, stream>>>(xbcs, dA, KVp);
    kv_reduce<<<(D_INNER * D_STATE / 4) / 256, 256, 0, stream>>>(KVp, KVTb);

    // 4) y1b = bf16( Cmat @ KVT^T )  (M=4096, N=2048, K=128); A = C-slice of xbcs
    gemm_bf16_pipe<128, 4, 1><<<(D_INNER / 128) * 32, 256, 0, stream>>>(
        xbcs + (D_INNER + D_STATE), CONV_DIM, KVTb, D_STATE, y1b, D_INNER);

    // 5) y = LN(y1 + D*x_in) * silu(z) -> bf16 yb
    ln_gate_kernel<<<SEQLEN, 256, 0, stream>>>(y1b, xbcs, zxb, Dp, ln_w, ln_b, yb);

    // 6) out = y @ W_out^T  (M=4096, N=1024, K=2048) -> 512 blocks (BN=64), fp32 out
    gemm_bf16_pipe<64, 64, 0><<<(DIM_IN / 64) * 32, 256, 0, stream>>>(
        yb, D_INNER, Woutb, D_INNER, out, DIM_IN);
}

// Round 9
// 199.390 us; speedup vs baseline: 5.2201x; 1.0444x over previous
//
#include <hip/hip_runtime.h>
#include <math.h>

#define SEQLEN    4096
#define DIM_IN    1024
#define D_INNER   2048
#define N_HEADS   32
#define D_STATE   128
#define CONV_DIM  2304      // D_INNER + 2*D_STATE
#define D_IN_PROJ 4384      // 2*D_INNER + 2*D_STATE + N_HEADS
#define PROJ_LD   4480      // padded to 35*128 so GEMM1 N-tiles need no guard
#define LN_EPS    1e-5f
#define KV_SPLIT  16        // L-chunks (256 l each) for the KV partial reduction

typedef __attribute__((ext_vector_type(8))) short bf16x8;
typedef __attribute__((ext_vector_type(4))) float f32x4;
typedef __attribute__((ext_vector_type(8))) short short8;

__device__ __forceinline__ ushort f2bf(float f) {
    union { float f; unsigned u; } v; v.f = f;
    unsigned u = v.u + 0x7FFFu + ((v.u >> 16) & 1u);   // RNE
    return (ushort)(u >> 16);
}
__device__ __forceinline__ float bf2f(ushort h) {
    union { unsigned u; float f; } v; v.u = ((unsigned)h) << 16;
    return v.f;
}

__device__ __forceinline__ void gload16(const void* g, void* l) {
    __builtin_amdgcn_global_load_lds(
        (const __attribute__((address_space(1))) void*)g,
        (__attribute__((address_space(3))) void*)l, 16, 0, 0);
}

// ---------------- fused fp32 -> bf16 converts (x, W_in padded, W_out) ----------------
#define XB_GROUPS   (SEQLEN * DIM_IN / 8)              // 65536
#define WIN_GROUPS  (PROJ_LD * DIM_IN / 8)             // 573440
#define WOUT_GROUPS (DIM_IN * D_INNER / 8)             // 262144
__global__ __launch_bounds__(256)
void cvt_all(const float* __restrict__ x, const float* __restrict__ W_in,
             const float* __restrict__ W_out,
             ushort* __restrict__ xb, ushort* __restrict__ Winb,
             ushort* __restrict__ Woutb) {
    int i = blockIdx.x * 256 + threadIdx.x;
    const float* src;
    ushort* dst;
    int gi;
    if (i < XB_GROUPS) {
        src = x; dst = xb; gi = i;
    } else if (i < XB_GROUPS + WIN_GROUPS) {
        gi = i - XB_GROUPS;
        int row = (gi * 8) >> 10;
        if (row >= D_IN_PROJ) {   // zero pad rows
            *reinterpret_cast<short8*>(&Winb[(size_t)gi * 8]) = (short8){0,0,0,0,0,0,0,0};
            return;
        }
        src = W_in; dst = Winb;
    } else if (i < XB_GROUPS + WIN_GROUPS + WOUT_GROUPS) {
        gi = i - (XB_GROUPS + WIN_GROUPS);
        src = W_out; dst = Woutb;
    } else return;
    float4 v0 = reinterpret_cast<const float4*>(src)[gi * 2];
    float4 v1 = reinterpret_cast<const float4*>(src)[gi * 2 + 1];
    short8 r;
    r[0] = f2bf(v0.x); r[1] = f2bf(v0.y); r[2] = f2bf(v0.z); r[3] = f2bf(v0.w);
    r[4] = f2bf(v1.x); r[5] = f2bf(v1.y); r[6] = f2bf(v1.z); r[7] = f2bf(v1.w);
    *reinterpret_cast<short8*>(&dst[(size_t)gi * 8]) = r;
}
#define CVT_TOTAL (XB_GROUPS + WIN_GROUPS + WOUT_GROUPS)

// ================= big-tile pipelined bf16 NT GEMM (GEMM1) =================
// BM=256, BN=128, BK=32, 4 waves, per-wave 128x64, ring-3 LDS, counted vmcnt(6),
// XOR bank swizzle, XCD swizzle (N-fastest within XCD: A-tile stays L2-resident).
template<int NT, int NTB>
__global__ __launch_bounds__(256, 2)
void gemm_bf16_big(const ushort* __restrict__ A, int lda,
                   const ushort* __restrict__ B, int ldb,
                   ushort* __restrict__ Cout, int ldc) {
    __shared__ __align__(16) ushort S[3][12288];   // 72 KB

    const int nwg = gridDim.x;
    const int wg  = blockIdx.x;
    const int swz = (wg & 7) * (nwg >> 3) + (wg >> 3);   // bijective, nwg%8==0
    const int m0 = (swz / NTB) * 256;     // N-fastest: m constant over NTB blocks
    const int n0 = (swz % NTB) * 128;

    const int tid  = threadIdx.x;
    const int wave = tid >> 6;
    const int lane = tid & 63;
    const int wm = (wave >> 1) * 128;
    const int wn = (wave & 1) * 64;
    const int r16 = lane & 15;
    const int kg  = lane >> 4;
    const int pkg = kg ^ ((r16 >> 1) & 3);

    f32x4 acc[8][4];
    #pragma unroll
    for (int i = 0; i < 8; ++i)
        #pragma unroll
        for (int j = 0; j < 4; ++j) acc[i][j] = (f32x4){0.f, 0.f, 0.f, 0.f};

    const int srow = lane >> 2;
    const int scol = ((lane & 3) ^ ((lane >> 3) & 3)) * 8;
    const ushort* gsrc[6];
    #pragma unroll
    for (int i = 0; i < 6; ++i) {
        int c = wave * 6 + i;
        gsrc[i] = (c < 16)
            ? A + (size_t)(m0 + c * 16 + srow) * lda + scol
            : B + (size_t)(n0 + (c - 16) * 16 + srow) * ldb + scol;
    }

#define STAGE_BIG(T, BUF)                                            \
    {                                                                \
        const int _k = (T) * 32;                                     \
        _Pragma("unroll")                                            \
        for (int i = 0; i < 6; ++i)                                  \
            gload16(gsrc[i] + _k, &S[BUF][(wave * 6 + i) * 512]);    \
    }

    STAGE_BIG(0, 0)
    STAGE_BIG(1, 1)

    int rb = 0;
    for (int t = 0; t < NT; ++t) {
        __builtin_amdgcn_sched_barrier(0);
        if (t + 1 < NT) {
            asm volatile("s_waitcnt vmcnt(6)" ::: "memory");
        } else {
            asm volatile("s_waitcnt vmcnt(0)" ::: "memory");
        }
        __builtin_amdgcn_s_barrier();
        __builtin_amdgcn_sched_barrier(0);

        if (t + 2 < NT) {
            int sb = rb + 2; if (sb >= 3) sb -= 3;
            STAGE_BIG(t + 2, sb)
        }

        const ushort* sp = &S[rb][0];
        bf16x8 b4[4];
        #pragma unroll
        for (int ni = 0; ni < 4; ++ni)
            b4[ni] = *reinterpret_cast<const bf16x8*>(
                &sp[8192 + (wn + ni * 16 + r16) * 32 + pkg * 8]);
        #pragma unroll
        for (int mh = 0; mh < 2; ++mh) {
            bf16x8 a4[4];
            #pragma unroll
            for (int i = 0; i < 4; ++i)
                a4[i] = *reinterpret_cast<const bf16x8*>(
                    &sp[(wm + (mh * 4 + i) * 16 + r16) * 32 + pkg * 8]);
            __builtin_amdgcn_s_setprio(1);
            #pragma unroll
            for (int i = 0; i < 4; ++i)
                #pragma unroll
                for (int ni = 0; ni < 4; ++ni)
                    acc[mh * 4 + i][ni] = __builtin_amdgcn_mfma_f32_16x16x32_bf16(
                        a4[i], b4[ni], acc[mh * 4 + i][ni], 0, 0, 0);
            __builtin_amdgcn_s_setprio(0);
        }
        rb = (rb == 2) ? 0 : rb + 1;
    }
#undef STAGE_BIG

    ushort* EP = &S[0][0];                 // 128*136 = 17408 ushort, padded stride
    __syncthreads();
    #pragma unroll
    for (int half = 0; half < 2; ++half) {
        if ((wave >> 1) == half) {
            #pragma unroll
            for (int mi = 0; mi < 8; ++mi)
                #pragma unroll
                for (int ni = 0; ni < 4; ++ni)
                    #pragma unroll
                    for (int r = 0; r < 4; ++r)
                        EP[(mi * 16 + kg * 4 + r) * 136 + wn + ni * 16 + r16] =
                            f2bf(acc[mi][ni][r]);
        }
        __syncthreads();
        #pragma unroll
        for (int i = 0; i < 8; ++i) {
            int idx = tid + 256 * i;
            int row = idx >> 4;
            int cb  = idx & 15;
            bf16x8 v = *reinterpret_cast<const bf16x8*>(&EP[row * 136 + cb * 8]);
            *reinterpret_cast<bf16x8*>(
                &Cout[(size_t)(m0 + half * 128 + row) * ldc + n0 + cb * 8]) = v;
        }
        __syncthreads();
    }
}

// ---------------- pipelined bf16 NT GEMM (GEMM2/3) ----------------
// BM=128, BN in {128,64}. Ring-3, counted vmcnt, XOR swizzle, N-fastest XCD swizzle.
template<int BN, int NT, int OUTBF, int NTB>
__global__ __launch_bounds__(256)
void gemm_bf16_pipe(const ushort* __restrict__ A, int lda,
                    const ushort* __restrict__ B, int ldb,
                    void* __restrict__ Cout, int ldc) {
    constexpr int NI  = BN / 32;
    constexpr int BNP = BN + 8;
    __shared__ __align__(16) ushort As[3][128 * 32];
    __shared__ __align__(16) ushort Bs[3][BN * 32];

    const int nwg = gridDim.x;
    const int wg  = blockIdx.x;
    const int swz = (wg & 7) * (nwg >> 3) + (wg >> 3);
    const int m0 = (swz / NTB) * 128;
    const int n0 = (swz % NTB) * BN;

    const int tid  = threadIdx.x;
    const int wave = tid >> 6;
    const int lane = tid & 63;
    const int wm = (wave & 1) * 64;
    const int wn = (wave >> 1) * (BN / 2);
    const int r16 = lane & 15;
    const int kg  = lane >> 4;
    const int pkg = kg ^ ((r16 >> 1) & 3);

    f32x4 acc[4][NI];
    #pragma unroll
    for (int i = 0; i < 4; ++i)
        #pragma unroll
        for (int j = 0; j < NI; ++j) acc[i][j] = (f32x4){0.f, 0.f, 0.f, 0.f};

    const int srow = lane >> 2;
    const int scol = ((lane & 3) ^ ((lane >> 3) & 3)) * 8;
    const int ca0 = wave * 2, ca1 = wave * 2 + 1;
    const ushort* gA0 = A + (size_t)(m0 + ca0 * 16 + srow) * lda + scol;
    const ushort* gA1 = A + (size_t)(m0 + ca1 * 16 + srow) * lda + scol;
    const ushort* gB0;
    const ushort* gB1 = nullptr;
    int cb0, cb1 = 0;
    if constexpr (BN == 128) {
        cb0 = wave * 2; cb1 = wave * 2 + 1;
        gB0 = B + (size_t)(n0 + cb0 * 16 + srow) * ldb + scol;
        gB1 = B + (size_t)(n0 + cb1 * 16 + srow) * ldb + scol;
    } else {
        cb0 = wave;
        gB0 = B + (size_t)(n0 + cb0 * 16 + srow) * ldb + scol;
    }

#define STAGE_STEP(T, BUF)                                          \
    {                                                               \
        const int _k = (T) * 32;                                    \
        gload16(gA0 + _k, &As[BUF][ca0 * 512]);                     \
        gload16(gA1 + _k, &As[BUF][ca1 * 512]);                     \
        gload16(gB0 + _k, &Bs[BUF][cb0 * 512]);                     \
        if constexpr (BN == 128) gload16(gB1 + _k, &Bs[BUF][cb1 * 512]); \
    }

    STAGE_STEP(0, 0)
    STAGE_STEP(1, 1)

    int rb = 0;
    for (int t = 0; t < NT; ++t) {
        __builtin_amdgcn_sched_barrier(0);
        if (t + 1 < NT) {
            if constexpr (BN == 128) asm volatile("s_waitcnt vmcnt(4)" ::: "memory");
            else                     asm volatile("s_waitcnt vmcnt(3)" ::: "memory");
        } else {
            asm volatile("s_waitcnt vmcnt(0)" ::: "memory");
        }
        __builtin_amdgcn_s_barrier();
        __builtin_amdgcn_sched_barrier(0);

        if (t + 2 < NT) {
            int sb = rb + 2; if (sb >= 3) sb -= 3;
            STAGE_STEP(t + 2, sb)
        }

        const ushort* ab = &As[rb][0];
        const ushort* bb = &Bs[rb][0];
        bf16x8 a[4], b[NI];
        #pragma unroll
        for (int mi = 0; mi < 4; ++mi)
            a[mi] = *reinterpret_cast<const bf16x8*>(&ab[(wm + mi * 16 + r16) * 32 + pkg * 8]);
        #pragma unroll
        for (int ni = 0; ni < NI; ++ni)
            b[ni] = *reinterpret_cast<const bf16x8*>(&bb[(wn + ni * 16 + r16) * 32 + pkg * 8]);

        __builtin_amdgcn_s_setprio(1);
        #pragma unroll
        for (int mi = 0; mi < 4; ++mi)
            #pragma unroll
            for (int ni = 0; ni < NI; ++ni)
                acc[mi][ni] = __builtin_amdgcn_mfma_f32_16x16x32_bf16(a[mi], b[ni], acc[mi][ni], 0, 0, 0);
        __builtin_amdgcn_s_setprio(0);

        rb = (rb == 2) ? 0 : rb + 1;
    }
#undef STAGE_STEP

    if constexpr (OUTBF) {
        ushort* EP = &As[0][0];
        ushort* outp = (ushort*)Cout;
        __syncthreads();
        #pragma unroll
        for (int half = 0; half < 2; ++half) {
            if ((wave & 1) == half) {
                #pragma unroll
                for (int mi = 0; mi < 4; ++mi)
                    #pragma unroll
                    for (int ni = 0; ni < NI; ++ni)
                        #pragma unroll
                        for (int r = 0; r < 4; ++r)
                            EP[(mi * 16 + kg * 4 + r) * BNP + wn + ni * 16 + r16] =
                                f2bf(acc[mi][ni][r]);
            }
            __syncthreads();
            #pragma unroll
            for (int i = 0; i < BN / 32; ++i) {
                int idx = tid + 256 * i;
                int row = idx / (BN / 8);
                int cb  = idx % (BN / 8);
                bf16x8 v = *reinterpret_cast<const bf16x8*>(&EP[row * BNP + cb * 8]);
                *reinterpret_cast<bf16x8*>(
                    &outp[(size_t)(m0 + half * 64 + row) * ldc + n0 + cb * 8]) = v;
            }
            __syncthreads();
        }
    } else {
        float* outp = (float*)Cout;
        #pragma unroll
        for (int mi = 0; mi < 4; ++mi)
            #pragma unroll
            for (int ni = 0; ni < NI; ++ni)
                #pragma unroll
                for (int r = 0; r < 4; ++r) {
                    int row = m0 + wm + mi * 16 + kg * 4 + r;
                    int col = n0 + wn + ni * 16 + r16;
                    outp[(size_t)row * ldc + col] = acc[mi][ni][r];
                }
    }
}

// ---------------- conv(width4, SAME) + SiLU ; softplus(dt)*A ; vectorized bf16 ----------------
__global__ __launch_bounds__(256)
void conv_silu_kernel(const ushort* __restrict__ zxb,
                      const float* __restrict__ conv_w,
                      const float* __restrict__ conv_b,
                      const float* __restrict__ dt_bias,
                      const float* __restrict__ A_log,
                      ushort* __restrict__ xbcs,
                      float* __restrict__ dA) {
    const int l = blockIdx.x;
    const ushort* base = zxb + (size_t)l * PROJ_LD + D_INNER;
    const short8 zero8 = (short8){0,0,0,0,0,0,0,0};
    for (int g = threadIdx.x; g < CONV_DIM / 8; g += 256) {
        const int c = g * 8;
        short8 xm = (l >= 1)
            ? *reinterpret_cast<const short8*>(base + c - PROJ_LD) : zero8;
        short8 x0 = *reinterpret_cast<const short8*>(base + c);
        short8 xp = (l + 1 < SEQLEN)
            ? *reinterpret_cast<const short8*>(base + c + PROJ_LD) : zero8;
        short8 xq = (l + 2 < SEQLEN)
            ? *reinterpret_cast<const short8*>(base + c + 2 * PROJ_LD) : zero8;
        float4 bia0 = *reinterpret_cast<const float4*>(&conv_b[c]);
        float4 bia1 = *reinterpret_cast<const float4*>(&conv_b[c + 4]);
        const float* bp = &bia0.x;
        short8 o;
        #pragma unroll
        for (int j = 0; j < 8; ++j) {
            float4 w = *reinterpret_cast<const float4*>(&conv_w[(c + j) * 4]);
            float acc = (j < 4 ? (&bia0.x)[j] : (&bia1.x)[j - 4]);
            acc += w.x * bf2f((ushort)xm[j]);
            acc += w.y * bf2f((ushort)x0[j]);
            acc += w.z * bf2f((ushort)xp[j]);
            acc += w.w * bf2f((ushort)xq[j]);
            float s = acc / (1.0f + expf(-acc));   // silu
            o[j] = f2bf(s);
        }
        (void)bp;
        *reinterpret_cast<short8*>(&xbcs[(size_t)l * CONV_DIM + c]) = o;
    }
    if (threadIdx.x < N_HEADS) {
        int h = threadIdx.x;
        float v = bf2f(zxb[(size_t)l * PROJ_LD + (D_IN_PROJ - N_HEADS) + h]) + dt_bias[h];
        float sp = (v > 20.0f) ? v : log1pf(expf(v));
        dA[l * N_HEADS + h] = sp * (-expf(A_log[h]));
    }
}

// ---------------- KV partials ----------------
__global__ __launch_bounds__(256)
void kv_kernel(const ushort* __restrict__ xbcs,
               const float* __restrict__ dA,
               float* __restrict__ KVp) {
    __shared__ float Vs[16][132];
    __shared__ float Bsm[16][132];
    const int hp0 = blockIdx.x * 128;
    const int lc0 = blockIdx.y * (SEQLEN / KV_SPLIT);
    const int tid = threadIdx.x;
    const int ty = tid >> 4, tx = tid & 15;
    float acc[8][8];
    #pragma unroll
    for (int i = 0; i < 8; ++i)
        #pragma unroll
        for (int j = 0; j < 8; ++j) acc[i][j] = 0.0f;

    for (int ls = 0; ls < SEQLEN / KV_SPLIT; ls += 16) {
        {
            int lrow = tid >> 4;
            int p8   = (tid & 15) * 8;
            int l = lc0 + ls + lrow;
            short8 v = *reinterpret_cast<const short8*>(
                &xbcs[(size_t)l * CONV_DIM + hp0 + p8]);
            float a = dA[l * N_HEADS + ((hp0 + p8) >> 6)];
            #pragma unroll
            for (int j = 0; j < 8; ++j) Vs[lrow][p8 + j] = bf2f((ushort)v[j]) * a;
            short8 b = *reinterpret_cast<const short8*>(
                &xbcs[(size_t)l * CONV_DIM + D_INNER + p8]);
            #pragma unroll
            for (int j = 0; j < 8; ++j) Bsm[lrow][p8 + j] = bf2f((ushort)b[j]);
        }
        __syncthreads();
        #pragma unroll
        for (int k = 0; k < 16; ++k) {
            float a[8], b[8];
            *reinterpret_cast<float4*>(&a[0]) = *reinterpret_cast<const float4*>(&Vs[k][ty * 8]);
            *reinterpret_cast<float4*>(&a[4]) = *reinterpret_cast<const float4*>(&Vs[k][ty * 8 + 4]);
            *reinterpret_cast<float4*>(&b[0]) = *reinterpret_cast<const float4*>(&Bsm[k][tx * 8]);
            *reinterpret_cast<float4*>(&b[4]) = *reinterpret_cast<const float4*>(&Bsm[k][tx * 8 + 4]);
            #pragma unroll
            for (int i = 0; i < 8; ++i)
                #pragma unroll
                for (int j = 0; j < 8; ++j)
                    acc[i][j] = fmaf(a[i], b[j], acc[i][j]);
        }
        __syncthreads();
    }
    float* dst = KVp + (size_t)blockIdx.y * (D_INNER * D_STATE);
    #pragma unroll
    for (int i = 0; i < 8; ++i) {
        int hp = hp0 + ty * 8 + i;
        #pragma unroll
        for (int j = 0; j < 8; j += 4) {
            float4 v = make_float4(acc[i][j], acc[i][j+1], acc[i][j+2], acc[i][j+3]);
            *reinterpret_cast<float4*>(&dst[(size_t)hp * D_STATE + tx * 8 + j]) = v;
        }
    }
}

// ---------------- reduce KV_SPLIT partial slices -> bf16 KVT ----------------
__global__ __launch_bounds__(256)
void kv_reduce(const float* __restrict__ KVp, ushort* __restrict__ KVTb) {
    int i = blockIdx.x * 256 + threadIdx.x;
    float4 s = make_float4(0.f, 0.f, 0.f, 0.f);
    #pragma unroll
    for (int c = 0; c < KV_SPLIT; ++c) {
        float4 v = reinterpret_cast<const float4*>(KVp + (size_t)c * (D_INNER * D_STATE))[i];
        s.x += v.x; s.y += v.y; s.z += v.z; s.w += v.w;
    }
    ushort4 o;
    o.x = f2bf(s.x); o.y = f2bf(s.y); o.z = f2bf(s.z); o.w = f2bf(s.w);
    *reinterpret_cast<ushort4*>(&KVTb[i * 4]) = o;
}

// ---------------- y = LN(y1 + D*x_in) * silu(z) -> bf16 ----------------
__global__ __launch_bounds__(256)
void ln_gate_kernel(const ushort* __restrict__ y1b,
                    const ushort* __restrict__ xbcs,
                    const ushort* __restrict__ zxb,
                    const float* __restrict__ Dp,
                    const float* __restrict__ ln_w,
                    const float* __restrict__ ln_b,
                    ushort* __restrict__ yb) {
    const int l = blockIdx.x;
    const int tid = threadIdx.x;
    const int c = tid * 8;
    float y[8], z[8];
    float sum = 0.f, sumsq = 0.f;
    {
        short8 v  = *reinterpret_cast<const short8*>(&y1b[(size_t)l * D_INNER + c]);
        short8 xi = *reinterpret_cast<const short8*>(&xbcs[(size_t)l * CONV_DIM + c]);
        short8 zz = *reinterpret_cast<const short8*>(&zxb[(size_t)l * PROJ_LD + c]);
        float d = Dp[c >> 6];
        #pragma unroll
        for (int j = 0; j < 8; ++j) {
            float yv = bf2f((ushort)v[j]) + bf2f((ushort)xi[j]) * d;
            y[j] = yv;
            z[j] = bf2f((ushort)zz[j]);
            sum += yv;
            sumsq += yv * yv;
        }
    }
    #pragma unroll
    for (int off = 32; off > 0; off >>= 1) {
        sum   += __shfl_down(sum, off);
        sumsq += __shfl_down(sumsq, off);
    }
    __shared__ float red[8];
    int wid = tid >> 6;
    if ((tid & 63) == 0) { red[wid] = sum; red[4 + wid] = sumsq; }
    __syncthreads();
    sum   = red[0] + red[1] + red[2] + red[3];
    sumsq = red[4] + red[5] + red[6] + red[7];
    float mu  = sum * (1.0f / D_INNER);
    float var = sumsq * (1.0f / D_INNER) - mu * mu;
    float rs  = rsqrtf(var + LN_EPS);
    short8 o;
    #pragma unroll
    for (int j = 0; j < 8; ++j) {
        float yn = (y[j] - mu) * rs * ln_w[c + j] + ln_b[c + j];
        float g  = z[j] / (1.0f + expf(-z[j]));
        o[j] = f2bf(yn * g);
    }
    *reinterpret_cast<short8*>(&yb[(size_t)l * D_INNER + c]) = o;
}

extern "C" void kernel_launch(void* const* d_in, const int* in_sizes, int n_in,
                              void* d_out, int out_size, void* d_ws, size_t ws_size,
                              hipStream_t stream) {
    const float* x       = (const float*)d_in[0];
    const float* W_in    = (const float*)d_in[1];
    const float* conv_w  = (const float*)d_in[2];
    const float* conv_b  = (const float*)d_in[3];
    const float* dt_bias = (const float*)d_in[4];
    const float* A_log   = (const float*)d_in[5];
    const float* Dp      = (const float*)d_in[6];
    const float* ln_w    = (const float*)d_in[7];
    const float* ln_b    = (const float*)d_in[8];
    const float* W_out   = (const float*)d_in[9];
    float* out = (float*)d_out;

    // workspace layout (bytes), all 256-aligned
    char* ws = (char*)d_ws;
    ushort* zxb   = (ushort*)ws;                       // 4096*4480*2 = 36,700,160
    ushort* xbcs  = (ushort*)(ws +  36700160);         // 4096*2304*2 = 18,874,368
    ushort* y1b   = (ushort*)(ws +  55574528);         // 4096*2048*2 = 16,777,216
    ushort* yb    = (ushort*)(ws +  72351744);         // 4096*2048*2 = 16,777,216
    float*  KVp   = (float*)(ws +  89128960);          // 16*2048*128*4 = 16,777,216
    float*  dA    = (float*)(ws + 105906176);          // 4096*32*4   =    524,288
    ushort* KVTb  = (ushort*)(ws + 106430464);         // 2048*128*2  =    524,288
    ushort* Woutb = (ushort*)(ws + 106954752);         // 1024*2048*2 =  4,194,304
    ushort* xb    = (ushort*)(ws + 111149056);         // 4096*1024*2 =  8,388,608
    ushort* Winb  = (ushort*)(ws + 119537664);         // 4480*1024*2 =  9,175,040

    // fused converts for GEMM1 + GEMM3 weights
    cvt_all<<<(CVT_TOTAL + 255) / 256, 256, 0, stream>>>(x, W_in, W_out, xb, Winb, Woutb);

    // 1) zxb = bf16( x @ W_in^T )   (M=4096, N=4480(pad), K=1024) -> 560 big blocks
    gemm_bf16_big<32, 35><<<16 * (PROJ_LD / 128), 256, 0, stream>>>(
        xb, DIM_IN, Winb, DIM_IN, zxb, PROJ_LD);

    // 2) conv + silu -> bf16 xbcs ; softplus(dt)*A -> dA
    conv_silu_kernel<<<SEQLEN, 256, 0, stream>>>(zxb, conv_w, conv_b, dt_bias, A_log,
                                                 xbcs, dA);

    // 3) KV partials (no atomics) then reduce -> bf16 KVT
    kv_kernel<<<dim3(16, KV_SPLIT), 256, 0, stream>>>(xbcs, dA, KVp);
    kv_reduce<<<(D_INNER * D_STATE / 4) / 256, 256, 0, stream>>>(KVp, KVTb);

    // 4) y1b = bf16( Cmat @ KVT^T )  (M=4096, N=2048, K=128); A = C-slice of xbcs
    gemm_bf16_pipe<128, 4, 1, 16><<<(D_INNER / 128) * 32, 256, 0, stream>>>(
        xbcs + (D_INNER + D_STATE), CONV_DIM, KVTb, D_STATE, y1b, D_INNER);

    // 5) y = LN(y1 + D*x_in) * silu(z) -> bf16 yb
    ln_gate_kernel<<<SEQLEN, 256, 0, stream>>>(y1b, xbcs, zxb, Dp, ln_w, ln_b, yb);

    // 6) out = y @ W_out^T  (M=4096, N=1024, K=2048) -> 512 blocks (BN=64), fp32 out
    gemm_bf16_pipe<64, 64, 0, 16><<<(DIM_IN / 64) * 32, 256, 0, stream>>>(
        yb, D_INNER, Woutb, D_INNER, out, DIM_IN);
}

// Round 10
// 196.232 us; speedup vs baseline: 5.3041x; 1.0161x over previous
//
#include <hip/hip_runtime.h>
#include <math.h>

#define SEQLEN    4096
#define DIM_IN    1024
#define D_INNER   2048
#define N_HEADS   32
#define D_STATE   128
#define CONV_DIM  2304      // D_INNER + 2*D_STATE
#define D_IN_PROJ 4384      // 2*D_INNER + 2*D_STATE + N_HEADS
#define PROJ_LD   4480      // padded to 35*128 so GEMM1 N-tiles need no guard
#define LN_EPS    1e-5f
#define KV_SPLIT  16        // L-chunks (256 l each) for the KV partial reduction

typedef __attribute__((ext_vector_type(8))) short bf16x8;
typedef __attribute__((ext_vector_type(4))) float f32x4;
typedef __attribute__((ext_vector_type(8))) short short8;

__device__ __forceinline__ ushort f2bf(float f) {
    union { float f; unsigned u; } v; v.f = f;
    unsigned u = v.u + 0x7FFFu + ((v.u >> 16) & 1u);   // RNE
    return (ushort)(u >> 16);
}
__device__ __forceinline__ float bf2f(ushort h) {
    union { unsigned u; float f; } v; v.u = ((unsigned)h) << 16;
    return v.f;
}

__device__ __forceinline__ void gload16(const void* g, void* l) {
    __builtin_amdgcn_global_load_lds(
        (const __attribute__((address_space(1))) void*)g,
        (__attribute__((address_space(3))) void*)l, 16, 0, 0);
}

// ---------------- fused fp32 -> bf16 converts (x, W_in padded, W_out) ----------------
#define XB_GROUPS   (SEQLEN * DIM_IN / 8)              // 65536
#define WIN_GROUPS  (PROJ_LD * DIM_IN / 8)             // 573440
#define WOUT_GROUPS (DIM_IN * D_INNER / 8)             // 262144
__global__ __launch_bounds__(256)
void cvt_all(const float* __restrict__ x, const float* __restrict__ W_in,
             const float* __restrict__ W_out,
             ushort* __restrict__ xb, ushort* __restrict__ Winb,
             ushort* __restrict__ Woutb) {
    int i = blockIdx.x * 256 + threadIdx.x;
    const float* src;
    ushort* dst;
    int gi;
    if (i < XB_GROUPS) {
        src = x; dst = xb; gi = i;
    } else if (i < XB_GROUPS + WIN_GROUPS) {
        gi = i - XB_GROUPS;
        int row = (gi * 8) >> 10;
        if (row >= D_IN_PROJ) {   // zero pad rows
            *reinterpret_cast<short8*>(&Winb[(size_t)gi * 8]) = (short8){0,0,0,0,0,0,0,0};
            return;
        }
        src = W_in; dst = Winb;
    } else if (i < XB_GROUPS + WIN_GROUPS + WOUT_GROUPS) {
        gi = i - (XB_GROUPS + WIN_GROUPS);
        src = W_out; dst = Woutb;
    } else return;
    float4 v0 = reinterpret_cast<const float4*>(src)[gi * 2];
    float4 v1 = reinterpret_cast<const float4*>(src)[gi * 2 + 1];
    short8 r;
    r[0] = f2bf(v0.x); r[1] = f2bf(v0.y); r[2] = f2bf(v0.z); r[3] = f2bf(v0.w);
    r[4] = f2bf(v1.x); r[5] = f2bf(v1.y); r[6] = f2bf(v1.z); r[7] = f2bf(v1.w);
    *reinterpret_cast<short8*>(&dst[(size_t)gi * 8]) = r;
}
#define CVT_TOTAL (XB_GROUPS + WIN_GROUPS + WOUT_GROUPS)

// ================= big-tile pipelined bf16 NT GEMM (GEMM1), 8 waves =================
// BM=256, BN=128, BK=32, 512 threads. Per-wave 64x64 output (4x4 frags, 8 ds_reads,
// 16 MFMA/step). Ring-3 LDS, counted vmcnt(3), XOR bank swizzle, N-fastest XCD
// swizzle. 16 waves/CU (2 blocks) for cross-wave overlap of the per-step barriers.
template<int NT, int NTB>
__global__ __launch_bounds__(512, 4)
void gemm_bf16_big(const ushort* __restrict__ A, int lda,
                   const ushort* __restrict__ B, int ldb,
                   ushort* __restrict__ Cout, int ldc) {
    __shared__ __align__(16) ushort S[3][12288];   // 72 KB

    const int nwg = gridDim.x;
    const int wg  = blockIdx.x;
    const int swz = (wg & 7) * (nwg >> 3) + (wg >> 3);   // bijective, nwg%8==0
    const int m0 = (swz / NTB) * 256;     // N-fastest: A-tile stays L2-resident
    const int n0 = (swz % NTB) * 128;

    const int tid  = threadIdx.x;
    const int wave = tid >> 6;           // 0..7
    const int lane = tid & 63;
    const int wr = wave >> 1;            // 0..3: rows wr*64
    const int wc = wave & 1;             // 0..1: cols wc*64
    const int r16 = lane & 15;
    const int kg  = lane >> 4;
    const int pkg = kg ^ ((r16 >> 1) & 3);   // T2 swizzled k-slot for ds_read

    f32x4 acc[4][4];
    #pragma unroll
    for (int i = 0; i < 4; ++i)
        #pragma unroll
        for (int j = 0; j < 4; ++j) acc[i][j] = (f32x4){0.f, 0.f, 0.f, 0.f};

    // staging: 24 chunks of 16 rows x 32 k (1 KB each); wave w stages chunks 3w..3w+2.
    // chunk c: c<16 -> A rows m0+16c.. ; else B rows n0+16(c-16).. ; LDS off = c*512.
    const int srow = lane >> 2;
    const int scol = ((lane & 3) ^ ((lane >> 3) & 3)) * 8;   // inverse-swizzled src slot
    const ushort* gsrc[3];
    #pragma unroll
    for (int i = 0; i < 3; ++i) {
        int c = wave * 3 + i;
        gsrc[i] = (c < 16)
            ? A + (size_t)(m0 + c * 16 + srow) * lda + scol
            : B + (size_t)(n0 + (c - 16) * 16 + srow) * ldb + scol;
    }

#define STAGE_BIG(T, BUF)                                            \
    {                                                                \
        const int _k = (T) * 32;                                     \
        _Pragma("unroll")                                            \
        for (int i = 0; i < 3; ++i)                                  \
            gload16(gsrc[i] + _k, &S[BUF][(wave * 3 + i) * 512]);    \
    }

    STAGE_BIG(0, 0)
    STAGE_BIG(1, 1)

    int rb = 0;
    for (int t = 0; t < NT; ++t) {
        __builtin_amdgcn_sched_barrier(0);
        if (t + 1 < NT) {   // steady: 6 outstanding; drain step t's 3
            asm volatile("s_waitcnt vmcnt(3)" ::: "memory");
        } else {
            asm volatile("s_waitcnt vmcnt(0)" ::: "memory");
        }
        __builtin_amdgcn_s_barrier();
        __builtin_amdgcn_sched_barrier(0);

        if (t + 2 < NT) {
            int sb = rb + 2; if (sb >= 3) sb -= 3;
            STAGE_BIG(t + 2, sb)
        }

        const ushort* sp = &S[rb][0];
        bf16x8 a4[4], b4[4];
        #pragma unroll
        for (int ni = 0; ni < 4; ++ni)
            b4[ni] = *reinterpret_cast<const bf16x8*>(
                &sp[8192 + (wc * 64 + ni * 16 + r16) * 32 + pkg * 8]);
        #pragma unroll
        for (int mi = 0; mi < 4; ++mi)
            a4[mi] = *reinterpret_cast<const bf16x8*>(
                &sp[(wr * 64 + mi * 16 + r16) * 32 + pkg * 8]);
        __builtin_amdgcn_s_setprio(1);
        #pragma unroll
        for (int mi = 0; mi < 4; ++mi)
            #pragma unroll
            for (int ni = 0; ni < 4; ++ni)
                acc[mi][ni] = __builtin_amdgcn_mfma_f32_16x16x32_bf16(
                    a4[mi], b4[ni], acc[mi][ni], 0, 0, 0);
        __builtin_amdgcn_s_setprio(0);

        rb = (rb == 2) ? 0 : rb + 1;
    }
#undef STAGE_BIG

    // epilogue: acc -> LDS bf16 (256 x 136 padded, 69.6 KB <= 72 KB ring) ->
    // coalesced 16B stores by all 512 threads
    ushort* EP = &S[0][0];
    __syncthreads();
    #pragma unroll
    for (int mi = 0; mi < 4; ++mi)
        #pragma unroll
        for (int ni = 0; ni < 4; ++ni)
            #pragma unroll
            for (int r = 0; r < 4; ++r)
                EP[(wr * 64 + mi * 16 + kg * 4 + r) * 136 + wc * 64 + ni * 16 + r16] =
                    f2bf(acc[mi][ni][r]);
    __syncthreads();
    #pragma unroll
    for (int i = 0; i < 8; ++i) {
        int idx = tid + 512 * i;           // 4096 chunks of 16B over 256x128
        int row = idx >> 4;
        int cb  = idx & 15;
        bf16x8 v = *reinterpret_cast<const bf16x8*>(&EP[row * 136 + cb * 8]);
        *reinterpret_cast<bf16x8*>(
            &Cout[(size_t)(m0 + row) * ldc + n0 + cb * 8]) = v;
    }
}

// ---------------- pipelined bf16 NT GEMM (GEMM2/3) ----------------
// BM=128, BN in {128,64}. Ring-3, counted vmcnt, XOR swizzle, N-fastest XCD swizzle.
template<int BN, int NT, int OUTBF, int NTB>
__global__ __launch_bounds__(256)
void gemm_bf16_pipe(const ushort* __restrict__ A, int lda,
                    const ushort* __restrict__ B, int ldb,
                    void* __restrict__ Cout, int ldc) {
    constexpr int NI  = BN / 32;
    constexpr int BNP = BN + 8;
    __shared__ __align__(16) ushort As[3][128 * 32];
    __shared__ __align__(16) ushort Bs[3][BN * 32];

    const int nwg = gridDim.x;
    const int wg  = blockIdx.x;
    const int swz = (wg & 7) * (nwg >> 3) + (wg >> 3);
    const int m0 = (swz / NTB) * 128;
    const int n0 = (swz % NTB) * BN;

    const int tid  = threadIdx.x;
    const int wave = tid >> 6;
    const int lane = tid & 63;
    const int wm = (wave & 1) * 64;
    const int wn = (wave >> 1) * (BN / 2);
    const int r16 = lane & 15;
    const int kg  = lane >> 4;
    const int pkg = kg ^ ((r16 >> 1) & 3);

    f32x4 acc[4][NI];
    #pragma unroll
    for (int i = 0; i < 4; ++i)
        #pragma unroll
        for (int j = 0; j < NI; ++j) acc[i][j] = (f32x4){0.f, 0.f, 0.f, 0.f};

    const int srow = lane >> 2;
    const int scol = ((lane & 3) ^ ((lane >> 3) & 3)) * 8;
    const int ca0 = wave * 2, ca1 = wave * 2 + 1;
    const ushort* gA0 = A + (size_t)(m0 + ca0 * 16 + srow) * lda + scol;
    const ushort* gA1 = A + (size_t)(m0 + ca1 * 16 + srow) * lda + scol;
    const ushort* gB0;
    const ushort* gB1 = nullptr;
    int cb0, cb1 = 0;
    if constexpr (BN == 128) {
        cb0 = wave * 2; cb1 = wave * 2 + 1;
        gB0 = B + (size_t)(n0 + cb0 * 16 + srow) * ldb + scol;
        gB1 = B + (size_t)(n0 + cb1 * 16 + srow) * ldb + scol;
    } else {
        cb0 = wave;
        gB0 = B + (size_t)(n0 + cb0 * 16 + srow) * ldb + scol;
    }

#define STAGE_STEP(T, BUF)                                          \
    {                                                               \
        const int _k = (T) * 32;                                    \
        gload16(gA0 + _k, &As[BUF][ca0 * 512]);                     \
        gload16(gA1 + _k, &As[BUF][ca1 * 512]);                     \
        gload16(gB0 + _k, &Bs[BUF][cb0 * 512]);                     \
        if constexpr (BN == 128) gload16(gB1 + _k, &Bs[BUF][cb1 * 512]); \
    }

    STAGE_STEP(0, 0)
    STAGE_STEP(1, 1)

    int rb = 0;
    for (int t = 0; t < NT; ++t) {
        __builtin_amdgcn_sched_barrier(0);
        if (t + 1 < NT) {
            if constexpr (BN == 128) asm volatile("s_waitcnt vmcnt(4)" ::: "memory");
            else                     asm volatile("s_waitcnt vmcnt(3)" ::: "memory");
        } else {
            asm volatile("s_waitcnt vmcnt(0)" ::: "memory");
        }
        __builtin_amdgcn_s_barrier();
        __builtin_amdgcn_sched_barrier(0);

        if (t + 2 < NT) {
            int sb = rb + 2; if (sb >= 3) sb -= 3;
            STAGE_STEP(t + 2, sb)
        }

        const ushort* ab = &As[rb][0];
        const ushort* bb = &Bs[rb][0];
        bf16x8 a[4], b[NI];
        #pragma unroll
        for (int mi = 0; mi < 4; ++mi)
            a[mi] = *reinterpret_cast<const bf16x8*>(&ab[(wm + mi * 16 + r16) * 32 + pkg * 8]);
        #pragma unroll
        for (int ni = 0; ni < NI; ++ni)
            b[ni] = *reinterpret_cast<const bf16x8*>(&bb[(wn + ni * 16 + r16) * 32 + pkg * 8]);

        __builtin_amdgcn_s_setprio(1);
        #pragma unroll
        for (int mi = 0; mi < 4; ++mi)
            #pragma unroll
            for (int ni = 0; ni < NI; ++ni)
                acc[mi][ni] = __builtin_amdgcn_mfma_f32_16x16x32_bf16(a[mi], b[ni], acc[mi][ni], 0, 0, 0);
        __builtin_amdgcn_s_setprio(0);

        rb = (rb == 2) ? 0 : rb + 1;
    }
#undef STAGE_STEP

    if constexpr (OUTBF) {
        ushort* EP = &As[0][0];
        ushort* outp = (ushort*)Cout;
        __syncthreads();
        #pragma unroll
        for (int half = 0; half < 2; ++half) {
            if ((wave & 1) == half) {
                #pragma unroll
                for (int mi = 0; mi < 4; ++mi)
                    #pragma unroll
                    for (int ni = 0; ni < NI; ++ni)
                        #pragma unroll
                        for (int r = 0; r < 4; ++r)
                            EP[(mi * 16 + kg * 4 + r) * BNP + wn + ni * 16 + r16] =
                                f2bf(acc[mi][ni][r]);
            }
            __syncthreads();
            #pragma unroll
            for (int i = 0; i < BN / 32; ++i) {
                int idx = tid + 256 * i;
                int row = idx / (BN / 8);
                int cb  = idx % (BN / 8);
                bf16x8 v = *reinterpret_cast<const bf16x8*>(&EP[row * BNP + cb * 8]);
                *reinterpret_cast<bf16x8*>(
                    &outp[(size_t)(m0 + half * 64 + row) * ldc + n0 + cb * 8]) = v;
            }
            __syncthreads();
        }
    } else {
        float* outp = (float*)Cout;
        #pragma unroll
        for (int mi = 0; mi < 4; ++mi)
            #pragma unroll
            for (int ni = 0; ni < NI; ++ni)
                #pragma unroll
                for (int r = 0; r < 4; ++r) {
                    int row = m0 + wm + mi * 16 + kg * 4 + r;
                    int col = n0 + wn + ni * 16 + r16;
                    outp[(size_t)row * ldc + col] = acc[mi][ni][r];
                }
    }
}

// ---------------- conv(width4, SAME) + SiLU ; softplus(dt)*A ; vectorized bf16 ----------------
__global__ __launch_bounds__(256)
void conv_silu_kernel(const ushort* __restrict__ zxb,
                      const float* __restrict__ conv_w,
                      const float* __restrict__ conv_b,
                      const float* __restrict__ dt_bias,
                      const float* __restrict__ A_log,
                      ushort* __restrict__ xbcs,
                      float* __restrict__ dA) {
    const int l = blockIdx.x;
    const ushort* base = zxb + (size_t)l * PROJ_LD + D_INNER;
    const short8 zero8 = (short8){0,0,0,0,0,0,0,0};
    for (int g = threadIdx.x; g < CONV_DIM / 8; g += 256) {
        const int c = g * 8;
        short8 xm = (l >= 1)
            ? *reinterpret_cast<const short8*>(base + c - PROJ_LD) : zero8;
        short8 x0 = *reinterpret_cast<const short8*>(base + c);
        short8 xp = (l + 1 < SEQLEN)
            ? *reinterpret_cast<const short8*>(base + c + PROJ_LD) : zero8;
        short8 xq = (l + 2 < SEQLEN)
            ? *reinterpret_cast<const short8*>(base + c + 2 * PROJ_LD) : zero8;
        float4 bia0 = *reinterpret_cast<const float4*>(&conv_b[c]);
        float4 bia1 = *reinterpret_cast<const float4*>(&conv_b[c + 4]);
        short8 o;
        #pragma unroll
        for (int j = 0; j < 8; ++j) {
            float4 w = *reinterpret_cast<const float4*>(&conv_w[(c + j) * 4]);
            float acc = (j < 4 ? (&bia0.x)[j] : (&bia1.x)[j - 4]);
            acc += w.x * bf2f((ushort)xm[j]);
            acc += w.y * bf2f((ushort)x0[j]);
            acc += w.z * bf2f((ushort)xp[j]);
            acc += w.w * bf2f((ushort)xq[j]);
            float s = acc / (1.0f + expf(-acc));   // silu
            o[j] = f2bf(s);
        }
        *reinterpret_cast<short8*>(&xbcs[(size_t)l * CONV_DIM + c]) = o;
    }
    if (threadIdx.x < N_HEADS) {
        int h = threadIdx.x;
        float v = bf2f(zxb[(size_t)l * PROJ_LD + (D_IN_PROJ - N_HEADS) + h]) + dt_bias[h];
        float sp = (v > 20.0f) ? v : log1pf(expf(v));
        dA[l * N_HEADS + h] = sp * (-expf(A_log[h]));
    }
}

// ---------------- KV partials ----------------
__global__ __launch_bounds__(256)
void kv_kernel(const ushort* __restrict__ xbcs,
               const float* __restrict__ dA,
               float* __restrict__ KVp) {
    __shared__ float Vs[16][132];
    __shared__ float Bsm[16][132];
    const int hp0 = blockIdx.x * 128;
    const int lc0 = blockIdx.y * (SEQLEN / KV_SPLIT);
    const int tid = threadIdx.x;
    const int ty = tid >> 4, tx = tid & 15;
    float acc[8][8];
    #pragma unroll
    for (int i = 0; i < 8; ++i)
        #pragma unroll
        for (int j = 0; j < 8; ++j) acc[i][j] = 0.0f;

    for (int ls = 0; ls < SEQLEN / KV_SPLIT; ls += 16) {
        {
            int lrow = tid >> 4;
            int p8   = (tid & 15) * 8;
            int l = lc0 + ls + lrow;
            short8 v = *reinterpret_cast<const short8*>(
                &xbcs[(size_t)l * CONV_DIM + hp0 + p8]);
            float a = dA[l * N_HEADS + ((hp0 + p8) >> 6)];
            #pragma unroll
            for (int j = 0; j < 8; ++j) Vs[lrow][p8 + j] = bf2f((ushort)v[j]) * a;
            short8 b = *reinterpret_cast<const short8*>(
                &xbcs[(size_t)l * CONV_DIM + D_INNER + p8]);
            #pragma unroll
            for (int j = 0; j < 8; ++j) Bsm[lrow][p8 + j] = bf2f((ushort)b[j]);
        }
        __syncthreads();
        #pragma unroll
        for (int k = 0; k < 16; ++k) {
            float a[8], b[8];
            *reinterpret_cast<float4*>(&a[0]) = *reinterpret_cast<const float4*>(&Vs[k][ty * 8]);
            *reinterpret_cast<float4*>(&a[4]) = *reinterpret_cast<const float4*>(&Vs[k][ty * 8 + 4]);
            *reinterpret_cast<float4*>(&b[0]) = *reinterpret_cast<const float4*>(&Bsm[k][tx * 8]);
            *reinterpret_cast<float4*>(&b[4]) = *reinterpret_cast<const float4*>(&Bsm[k][tx * 8 + 4]);
            #pragma unroll
            for (int i = 0; i < 8; ++i)
                #pragma unroll
                for (int j = 0; j < 8; ++j)
                    acc[i][j] = fmaf(a[i], b[j], acc[i][j]);
        }
        __syncthreads();
    }
    float* dst = KVp + (size_t)blockIdx.y * (D_INNER * D_STATE);
    #pragma unroll
    for (int i = 0; i < 8; ++i) {
        int hp = hp0 + ty * 8 + i;
        #pragma unroll
        for (int j = 0; j < 8; j += 4) {
            float4 v = make_float4(acc[i][j], acc[i][j+1], acc[i][j+2], acc[i][j+3]);
            *reinterpret_cast<float4*>(&dst[(size_t)hp * D_STATE + tx * 8 + j]) = v;
        }
    }
}

// ---------------- reduce KV_SPLIT partial slices -> bf16 KVT ----------------
__global__ __launch_bounds__(256)
void kv_reduce(const float* __restrict__ KVp, ushort* __restrict__ KVTb) {
    int i = blockIdx.x * 256 + threadIdx.x;
    float4 s = make_float4(0.f, 0.f, 0.f, 0.f);
    #pragma unroll
    for (int c = 0; c < KV_SPLIT; ++c) {
        float4 v = reinterpret_cast<const float4*>(KVp + (size_t)c * (D_INNER * D_STATE))[i];
        s.x += v.x; s.y += v.y; s.z += v.z; s.w += v.w;
    }
    ushort4 o;
    o.x = f2bf(s.x); o.y = f2bf(s.y); o.z = f2bf(s.z); o.w = f2bf(s.w);
    *reinterpret_cast<ushort4*>(&KVTb[i * 4]) = o;
}

// ---------------- y = LN(y1 + D*x_in) * silu(z) -> bf16 ----------------
__global__ __launch_bounds__(256)
void ln_gate_kernel(const ushort* __restrict__ y1b,
                    const ushort* __restrict__ xbcs,
                    const ushort* __restrict__ zxb,
                    const float* __restrict__ Dp,
                    const float* __restrict__ ln_w,
                    const float* __restrict__ ln_b,
                    ushort* __restrict__ yb) {
    const int l = blockIdx.x;
    const int tid = threadIdx.x;
    const int c = tid * 8;
    float y[8], z[8];
    float sum = 0.f, sumsq = 0.f;
    {
        short8 v  = *reinterpret_cast<const short8*>(&y1b[(size_t)l * D_INNER + c]);
        short8 xi = *reinterpret_cast<const short8*>(&xbcs[(size_t)l * CONV_DIM + c]);
        short8 zz = *reinterpret_cast<const short8*>(&zxb[(size_t)l * PROJ_LD + c]);
        float d = Dp[c >> 6];
        #pragma unroll
        for (int j = 0; j < 8; ++j) {
            float yv = bf2f((ushort)v[j]) + bf2f((ushort)xi[j]) * d;
            y[j] = yv;
            z[j] = bf2f((ushort)zz[j]);
            sum += yv;
            sumsq += yv * yv;
        }
    }
    #pragma unroll
    for (int off = 32; off > 0; off >>= 1) {
        sum   += __shfl_down(sum, off);
        sumsq += __shfl_down(sumsq, off);
    }
    __shared__ float red[8];
    int wid = tid >> 6;
    if ((tid & 63) == 0) { red[wid] = sum; red[4 + wid] = sumsq; }
    __syncthreads();
    sum   = red[0] + red[1] + red[2] + red[3];
    sumsq = red[4] + red[5] + red[6] + red[7];
    float mu  = sum * (1.0f / D_INNER);
    float var = sumsq * (1.0f / D_INNER) - mu * mu;
    float rs  = rsqrtf(var + LN_EPS);
    short8 o;
    #pragma unroll
    for (int j = 0; j < 8; ++j) {
        float yn = (y[j] - mu) * rs * ln_w[c + j] + ln_b[c + j];
        float g  = z[j] / (1.0f + expf(-z[j]));
        o[j] = f2bf(yn * g);
    }
    *reinterpret_cast<short8*>(&yb[(size_t)l * D_INNER + c]) = o;
}

extern "C" void kernel_launch(void* const* d_in, const int* in_sizes, int n_in,
                              void* d_out, int out_size, void* d_ws, size_t ws_size,
                              hipStream_t stream) {
    const float* x       = (const float*)d_in[0];
    const float* W_in    = (const float*)d_in[1];
    const float* conv_w  = (const float*)d_in[2];
    const float* conv_b  = (const float*)d_in[3];
    const float* dt_bias = (const float*)d_in[4];
    const float* A_log   = (const float*)d_in[5];
    const float* Dp      = (const float*)d_in[6];
    const float* ln_w    = (const float*)d_in[7];
    const float* ln_b    = (const float*)d_in[8];
    const float* W_out   = (const float*)d_in[9];
    float* out = (float*)d_out;

    // workspace layout (bytes), all 256-aligned
    char* ws = (char*)d_ws;
    ushort* zxb   = (ushort*)ws;                       // 4096*4480*2 = 36,700,160
    ushort* xbcs  = (ushort*)(ws +  36700160);         // 4096*2304*2 = 18,874,368
    ushort* y1b   = (ushort*)(ws +  55574528);         // 4096*2048*2 = 16,777,216
    ushort* yb    = (ushort*)(ws +  72351744);         // 4096*2048*2 = 16,777,216
    float*  KVp   = (float*)(ws +  89128960);          // 16*2048*128*4 = 16,777,216
    float*  dA    = (float*)(ws + 105906176);          // 4096*32*4   =    524,288
    ushort* KVTb  = (ushort*)(ws + 106430464);         // 2048*128*2  =    524,288
    ushort* Woutb = (ushort*)(ws + 106954752);         // 1024*2048*2 =  4,194,304
    ushort* xb    = (ushort*)(ws + 111149056);         // 4096*1024*2 =  8,388,608
    ushort* Winb  = (ushort*)(ws + 119537664);         // 4480*1024*2 =  9,175,040

    // fused converts for GEMM1 + GEMM3 weights
    cvt_all<<<(CVT_TOTAL + 255) / 256, 256, 0, stream>>>(x, W_in, W_out, xb, Winb, Woutb);

    // 1) zxb = bf16( x @ W_in^T )   (M=4096, N=4480(pad), K=1024) -> 560 blocks x 512thr
    gemm_bf16_big<32, 35><<<16 * (PROJ_LD / 128), 512, 0, stream>>>(
        xb, DIM_IN, Winb, DIM_IN, zxb, PROJ_LD);

    // 2) conv + silu -> bf16 xbcs ; softplus(dt)*A -> dA
    conv_silu_kernel<<<SEQLEN, 256, 0, stream>>>(zxb, conv_w, conv_b, dt_bias, A_log,
                                                 xbcs, dA);

    // 3) KV partials (no atomics) then reduce -> bf16 KVT
    kv_kernel<<<dim3(16, KV_SPLIT), 256, 0, stream>>>(xbcs, dA, KVp);
    kv_reduce<<<(D_INNER * D_STATE / 4) / 256, 256, 0, stream>>>(KVp, KVTb);

    // 4) y1b = bf16( Cmat @ KVT^T )  (M=4096, N=2048, K=128); A = C-slice of xbcs
    gemm_bf16_pipe<128, 4, 1, 16><<<(D_INNER / 128) * 32, 256, 0, stream>>>(
        xbcs + (D_INNER + D_STATE), CONV_DIM, KVTb, D_STATE, y1b, D_INNER);

    // 5) y = LN(y1 + D*x_in) * silu(z) -> bf16 yb
    ln_gate_kernel<<<SEQLEN, 256, 0, stream>>>(y1b, xbcs, zxb, Dp, ln_w, ln_b, yb);

    // 6) out = y @ W_out^T  (M=4096, N=1024, K=2048) -> 512 blocks (BN=64), fp32 out
    gemm_bf16_pipe<64, 64, 0, 16><<<(DIM_IN / 64) * 32, 256, 0, stream>>>(
        yb, D_INNER, Woutb, D_INNER, out, DIM_IN);
}